// Round 1
// baseline (2331.970 us; speedup 1.0000x reference)
//
#include <hip/hip_runtime.h>
#include <cstddef>

// ---- problem constants ----
constexpr int Bb = 4, Ls = 512, Vv = 256, DMc = 256, DIc = 512, Nn = 16;
constexpr int DTRc = 16, NLc = 4, HIDc = 512;
constexpr int ROWS = Bb * Ls;  // 2048

// per-direction buffer sizes (floats)
constexpr size_t SZ_X  = (size_t)ROWS * DMc;      // 524288
constexpr size_t SZ_XR = (size_t)ROWS * 2 * DIc;  // 2097152
constexpr size_t SZ_XC = (size_t)ROWS * DIc;      // 1048576
constexpr size_t SZ_XD = (size_t)ROWS * 48;       // 98304

// workspace layout (float offsets)
constexpr size_t X_OFF    = 0;
constexpr size_t RES_OFF  = SZ_X;
constexpr size_t O_OFF    = 2 * SZ_X;              // 2 dirs
constexpr size_t XLN_OFF  = 4 * SZ_X;              // 2 dirs
constexpr size_t XR_OFF   = 6 * SZ_X;              // 2 dirs x SZ_XR
constexpr size_t XC_OFF   = XR_OFF + 2 * SZ_XR;    // 2 dirs
constexpr size_t XDBL_OFF = XC_OFF + 2 * SZ_XC;    // 2 dirs
constexpr size_t DELTA_OFF= XDBL_OFF + 2 * SZ_XD;  // 2 dirs
constexpr size_t YG_OFF   = DELTA_OFF + 2 * SZ_XC; // 2 dirs
// MLP buffers alias XR region (dead after scan epilogue)
constexpr size_t HN_OFF = XR_OFF;
constexpr size_t H1_OFF = XR_OFF + SZ_X;
constexpr size_t H2_OFF = XR_OFF + 2 * SZ_X;

// ---------------- generic f32 GEMM: C = A @ W^T + bias, act ----------------
// A: M x K (lda), W: N x K (ldw), C: M x N (ldc). z-batched via strides.
// ACT: 0=none, 1=relu, 2=softplus
template <int ACT>
__global__ __launch_bounds__(256) void gemm_f32(
    const float* __restrict__ A, int lda, long sA,
    const float* __restrict__ W, int ldw, long sW,
    const float* __restrict__ bias, long sB,
    float* __restrict__ C, int ldc, long sC,
    int M, int N, int K) {
  int z = blockIdx.z;
  A += (size_t)z * sA;
  W += (size_t)z * sW;
  if (bias) bias += (size_t)z * sB;
  C += (size_t)z * sC;

  __shared__ float As[64][17];
  __shared__ float Ws[64][17];
  int tid = threadIdx.x;
  int m0 = blockIdx.y * 64, n0 = blockIdx.x * 64;
  int tx = tid & 15, ty = tid >> 4;
  int lr = tid >> 2;         // 0..63 tile row to load
  int lk = (tid & 3) * 4;    // k offset within 16-chunk

  float acc[4][4] = {};
  for (int k0 = 0; k0 < K; k0 += 16) {
    {
      int r = m0 + lr;
      float4 v = make_float4(0.f, 0.f, 0.f, 0.f);
      if (r < M) v = *reinterpret_cast<const float4*>(A + (size_t)r * lda + k0 + lk);
      As[lr][lk + 0] = v.x; As[lr][lk + 1] = v.y; As[lr][lk + 2] = v.z; As[lr][lk + 3] = v.w;
      int rn = n0 + lr;
      float4 w = make_float4(0.f, 0.f, 0.f, 0.f);
      if (rn < N) w = *reinterpret_cast<const float4*>(W + (size_t)rn * ldw + k0 + lk);
      Ws[lr][lk + 0] = w.x; Ws[lr][lk + 1] = w.y; Ws[lr][lk + 2] = w.z; Ws[lr][lk + 3] = w.w;
    }
    __syncthreads();
#pragma unroll
    for (int kk = 0; kk < 16; kk++) {
      float a[4], b[4];
#pragma unroll
      for (int i = 0; i < 4; i++) a[i] = As[ty * 4 + i][kk];
#pragma unroll
      for (int j = 0; j < 4; j++) b[j] = Ws[tx * 4 + j][kk];
#pragma unroll
      for (int i = 0; i < 4; i++)
#pragma unroll
        for (int j = 0; j < 4; j++) acc[i][j] += a[i] * b[j];
    }
    __syncthreads();
  }
#pragma unroll
  for (int i = 0; i < 4; i++) {
    int row = m0 + ty * 4 + i;
    if (row >= M) continue;
#pragma unroll
    for (int j = 0; j < 4; j++) {
      int col = n0 + tx * 4 + j;
      if (col >= N) continue;
      float v = acc[i][j] + (bias ? bias[col] : 0.f);
      if (ACT == 1) v = fmaxf(v, 0.f);
      if (ACT == 2) v = fmaxf(v, 0.f) + log1pf(__expf(-fabsf(v)));
      C[(size_t)row * ldc + col] = v;
    }
  }
}

// ---------------- block reduce (256 threads, 2 values) ----------------
__device__ __forceinline__ void block_reduce_2(float& a, float& b, float* sa, float* sb) {
#pragma unroll
  for (int m = 32; m >= 1; m >>= 1) {
    a += __shfl_xor(a, m);
    b += __shfl_xor(b, m);
  }
  int wid = threadIdx.x >> 6, lane = threadIdx.x & 63;
  if (lane == 0) { sa[wid] = a; sb[wid] = b; }
  __syncthreads();
  a = sa[0] + sa[1] + sa[2] + sa[3];
  b = sb[0] + sb[1] + sb[2] + sb[3];
}

// ---------------- LN over DM (z = dir) ----------------
__global__ __launch_bounds__(256) void ln_dm_k(
    const float* __restrict__ x, const float* __restrict__ g,
    const float* __restrict__ bt, float* __restrict__ xln, int layer) {
  int dir = blockIdx.z;
  g += (size_t)(dir * NLc + layer) * DMc;
  bt += (size_t)(dir * NLc + layer) * DMc;
  float* out = xln + (size_t)dir * SZ_X;
  int row = blockIdx.x, t = threadIdx.x;
  float v = x[(size_t)row * DMc + t];
  float a = v, q = v * v;
  __shared__ float sa[4], sb[4];
  block_reduce_2(a, q, sa, sb);
  float mu = a * (1.f / DMc);
  float var = q * (1.f / DMc) - mu * mu;
  float inv = rsqrtf(var + 1e-5f);
  out[(size_t)row * DMc + t] = (v - mu) * inv * g[t] + bt[t];
}

// ---------------- final LN(x + resid) ----------------
__global__ __launch_bounds__(256) void ln_final_k(
    const float* __restrict__ x, const float* __restrict__ resid,
    const float* __restrict__ g, const float* __restrict__ bt,
    float* __restrict__ out) {
  int row = blockIdx.x, t = threadIdx.x;
  float v = x[(size_t)row * DMc + t] + resid[(size_t)row * DMc + t];
  float a = v, q = v * v;
  __shared__ float sa[4], sb[4];
  block_reduce_2(a, q, sa, sb);
  float mu = a * (1.f / DMc);
  float var = q * (1.f / DMc) - mu * mu;
  float inv = rsqrtf(var + 1e-5f);
  out[(size_t)row * DMc + t] = (v - mu) * inv * g[t] + bt[t];
}

// ---------------- causal depthwise conv (DC=4) + SiLU (z = dir) ----------------
__global__ __launch_bounds__(256) void conv_silu_k(
    const float* __restrict__ xr, const float* __restrict__ cw,
    const float* __restrict__ cb, float* __restrict__ xc, int layer) {
  int dir = blockIdx.z;
  const float* xin = xr + (size_t)dir * SZ_XR;  // cols 0..511 of 1024-wide rows
  const float* w = cw + (size_t)(dir * NLc + layer) * DIc * 4;
  const float* bb = cb + (size_t)(dir * NLc + layer) * DIc;
  float* out = xc + (size_t)dir * SZ_XC;
  int gid = blockIdx.x * 256 + threadIdx.x;  // < ROWS*DI
  int d = gid & 511, row = gid >> 9, l = row & 511;
  float w0 = w[d * 4 + 0], w1 = w[d * 4 + 1], w2 = w[d * 4 + 2], w3 = w[d * 4 + 3];
  float acc = bb[d];
  if (dir == 0) {  // out[l] = sum_k w[k]*x[l-3+k]
    acc += w3 * xin[(size_t)row * 1024 + d];
    if (l >= 1) acc += w2 * xin[(size_t)(row - 1) * 1024 + d];
    if (l >= 2) acc += w1 * xin[(size_t)(row - 2) * 1024 + d];
    if (l >= 3) acc += w0 * xin[(size_t)(row - 3) * 1024 + d];
  } else {         // reversed seq: out[l] = sum_k w[k]*x[l+3-k]
    acc += w3 * xin[(size_t)row * 1024 + d];
    if (l + 1 < Ls) acc += w2 * xin[(size_t)(row + 1) * 1024 + d];
    if (l + 2 < Ls) acc += w1 * xin[(size_t)(row + 2) * 1024 + d];
    if (l + 3 < Ls) acc += w0 * xin[(size_t)(row + 3) * 1024 + d];
  }
  out[(size_t)row * DIc + d] = acc * (1.f / (1.f + __expf(-acc)));
}

// ---------------- selective scan + gating (z = dir) ----------------
// thread = one (b, d, n) chain; 16 n-lanes shfl-reduced; n==0 writes gated y
__global__ __launch_bounds__(256) void scan_k(
    const float* __restrict__ delta, const float* __restrict__ xc,
    const float* __restrict__ xdbl, const float* __restrict__ xr,
    const float* __restrict__ A_log, const float* __restrict__ Dp,
    float* __restrict__ yg, int layer) {
  int dir = blockIdx.z;
  const float* dlt = delta + (size_t)dir * SZ_XC;
  const float* u   = xc + (size_t)dir * SZ_XC;
  const float* xd  = xdbl + (size_t)dir * SZ_XD;
  const float* res = xr + (size_t)dir * SZ_XR;
  float* out = yg + (size_t)dir * SZ_XC;
  int t = threadIdx.x;
  int n = t & 15, dsub = t >> 4;
  int b = blockIdx.x >> 5, dtile = blockIdx.x & 31;
  int d = dtile * 16 + dsub;
  float Adn = -__expf(A_log[((size_t)(dir * NLc + layer) * DIc + d) * Nn + n]);
  float Dd = Dp[(size_t)(dir * NLc + layer) * DIc + d];
  int l0 = dir ? (Ls - 1) : 0;
  int step = dir ? -1 : 1;
  size_t base = (size_t)b * Ls;
  float s = 0.f;
  int idx = (int)base + l0;
  float dv = dlt[(size_t)idx * DIc + d];
  float uv = u[(size_t)idx * DIc + d];
  float bm = xd[(size_t)idx * 48 + 16 + n];
  float cm = xd[(size_t)idx * 48 + 32 + n];
  for (int tt = 0; tt < Ls; tt++) {
    int l = l0 + tt * step;
    float dv2 = 0.f, uv2 = 0.f, bm2 = 0.f, cm2 = 0.f;
    if (tt + 1 < Ls) {  // prefetch next step
      int idx2 = (int)base + l + step;
      dv2 = dlt[(size_t)idx2 * DIc + d];
      uv2 = u[(size_t)idx2 * DIc + d];
      bm2 = xd[(size_t)idx2 * 48 + 16 + n];
      cm2 = xd[(size_t)idx2 * 48 + 32 + n];
    }
    float dA = __expf(dv * Adn);
    s = dA * s + dv * bm * uv;
    float v = s * cm;
    v += __shfl_xor(v, 1); v += __shfl_xor(v, 2);
    v += __shfl_xor(v, 4); v += __shfl_xor(v, 8);
    if (n == 0) {
      int idx3 = (int)base + l;
      float rv = res[(size_t)idx3 * 1024 + DIc + d];
      float sig = 1.f / (1.f + __expf(-rv));
      out[(size_t)idx3 * DIc + d] = (v + uv * Dd) * (rv * sig);
    }
    dv = dv2; uv = uv2; bm = bm2; cm = cm2;
  }
}

// ---------------- combine: x = 3x + o0 + o1 ----------------
__global__ __launch_bounds__(256) void combine_k(float* __restrict__ x,
                                                 const float* __restrict__ o) {
  size_t g = (size_t)blockIdx.x * 256 + threadIdx.x;
  x[g] = 3.f * x[g] + o[g] + o[g + SZ_X];
}

// ---------------- copy ----------------
__global__ __launch_bounds__(256) void copy_k(const float* __restrict__ a,
                                              float* __restrict__ b) {
  size_t g = (size_t)blockIdx.x * 256 + threadIdx.x;
  b[g] = a[g];
}

// ---------------- MLP norm over L (transposed read); use_ln ? LN : RMS ----------------
__global__ __launch_bounds__(256) void mlp_norm_k(
    const float* __restrict__ x, const float* __restrict__ w,
    const float* __restrict__ bb, float* __restrict__ hn, int use_ln) {
  int r = blockIdx.x;           // b*DM + m
  int b = r >> 8, m = r & 255;
  int t = threadIdx.x;
  const float* xb = x + (size_t)b * Ls * DMc + m;
  float v0 = xb[(size_t)t * DMc];
  float v1 = xb[(size_t)(t + 256) * DMc];
  float a = v0 + v1, q = v0 * v0 + v1 * v1;
  __shared__ float sa[4], sb[4];
  block_reduce_2(a, q, sa, sb);
  float mu = use_ln ? a * (1.f / Ls) : 0.f;
  float var = q * (1.f / Ls) - mu * mu;
  float inv = rsqrtf(var + 1e-5f);
  float* o = hn + (size_t)r * Ls;
  o[t] = (v0 - mu) * inv * w[t] + (use_ln ? bb[t] : 0.f);
  o[t + 256] = (v1 - mu) * inv * w[t + 256] + (use_ln ? bb[t + 256] : 0.f);
}

// ---------------- add-back: x[b,l,m] += h2[(b*DM+m)*L + l] ----------------
__global__ __launch_bounds__(256) void addback_k(float* __restrict__ x,
                                                 const float* __restrict__ h2) {
  size_t g = (size_t)blockIdx.x * 256 + threadIdx.x;
  int m = (int)(g & 255);
  int r = (int)(g >> 8);
  int l = r & 511, b = r >> 9;
  x[g] += h2[((size_t)(b * DMc + m)) * Ls + l];
}

// =======================================================================
extern "C" void kernel_launch(void* const* d_in, const int* in_sizes, int n_in,
                              void* d_out, int out_size, void* d_ws, size_t ws_size,
                              hipStream_t stream) {
  const float* input_ids = (const float*)d_in[0];
  const float* emb_W     = (const float*)d_in[1];
  const float* emb_b     = (const float*)d_in[2];
  const float* ln_g      = (const float*)d_in[3];
  const float* ln_b      = (const float*)d_in[4];
  const float* inproj_W  = (const float*)d_in[5];
  const float* inproj_b  = (const float*)d_in[6];
  const float* conv_w    = (const float*)d_in[7];
  const float* conv_b    = (const float*)d_in[8];
  const float* xproj_W   = (const float*)d_in[9];
  const float* dtproj_W  = (const float*)d_in[10];
  const float* dtproj_b  = (const float*)d_in[11];
  const float* outproj_W = (const float*)d_in[12];
  const float* outproj_b = (const float*)d_in[13];
  const float* A_log     = (const float*)d_in[14];
  const float* Dp        = (const float*)d_in[15];
  const float* lin_norm_w= (const float*)d_in[16];
  const float* lin_norm_b= (const float*)d_in[17];
  const float* lin_W1    = (const float*)d_in[18];
  const float* lin_b1    = (const float*)d_in[19];
  const float* lin_W2    = (const float*)d_in[20];
  const float* lin_b2    = (const float*)d_in[21];
  const float* normf_g   = (const float*)d_in[22];
  const float* normf_b   = (const float*)d_in[23];
  float* out = (float*)d_out;

  float* ws    = (float*)d_ws;
  float* x     = ws + X_OFF;
  float* resid = ws + RES_OFF;
  float* o     = ws + O_OFF;
  float* xln   = ws + XLN_OFF;
  float* xr    = ws + XR_OFF;
  float* xc    = ws + XC_OFF;
  float* xdbl  = ws + XDBL_OFF;
  float* delta = ws + DELTA_OFF;
  float* yg    = ws + YG_OFF;
  float* hn    = ws + HN_OFF;
  float* h1    = ws + H1_OFF;
  float* h2    = ws + H2_OFF;

  // 1. embedding: x = ids @ emb_W^T + emb_b   (2048x256x256)
  gemm_f32<0><<<dim3(DMc / 64, ROWS / 64, 1), 256, 0, stream>>>(
      input_ids, Vv, 0, emb_W, Vv, 0, emb_b, 0, x, DMc, 0, ROWS, DMc, Vv);
  copy_k<<<(int)(SZ_X / 256), 256, 0, stream>>>(x, resid);

  for (int i = 0; i < NLc; i++) {
    // LN per dir
    ln_dm_k<<<dim3(ROWS, 1, 2), 256, 0, stream>>>(x, ln_g, ln_b, xln, i);
    // inproj: 2048 x 1024 x 256 (both dirs)
    gemm_f32<0><<<dim3(16, ROWS / 64, 2), 256, 0, stream>>>(
        xln, DMc, (long)SZ_X,
        inproj_W + (size_t)i * 2 * DIc * DMc, DMc, (long)NLc * 2 * DIc * DMc,
        inproj_b + (size_t)i * 2 * DIc, (long)NLc * 2 * DIc,
        xr, 2 * DIc, (long)SZ_XR, ROWS, 2 * DIc, DMc);
    // depthwise causal conv + SiLU
    conv_silu_k<<<dim3(ROWS * DIc / 256, 1, 2), 256, 0, stream>>>(xr, conv_w, conv_b, xc, i);
    // xproj: 2048 x 48 x 512
    gemm_f32<0><<<dim3(1, ROWS / 64, 2), 256, 0, stream>>>(
        xc, DIc, (long)SZ_XC,
        xproj_W + (size_t)i * 48 * DIc, DIc, (long)NLc * 48 * DIc,
        nullptr, 0, xdbl, 48, (long)SZ_XD, ROWS, 48, DIc);
    // dtproj + softplus: 2048 x 512 x 16
    gemm_f32<2><<<dim3(8, ROWS / 64, 2), 256, 0, stream>>>(
        xdbl, 48, (long)SZ_XD,
        dtproj_W + (size_t)i * DIc * DTRc, DTRc, (long)NLc * DIc * DTRc,
        dtproj_b + (size_t)i * DIc, (long)NLc * DIc,
        delta, DIc, (long)SZ_XC, ROWS, DIc, DTRc);
    // selective scan + gate
    scan_k<<<dim3(Bb * (DIc / 16), 1, 2), 256, 0, stream>>>(
        delta, xc, xdbl, xr, A_log, Dp, yg, i);
    // outproj: 2048 x 256 x 512
    gemm_f32<0><<<dim3(4, ROWS / 64, 2), 256, 0, stream>>>(
        yg, DIc, (long)SZ_XC,
        outproj_W + (size_t)i * DMc * DIc, DIc, (long)NLc * DMc * DIc,
        outproj_b + (size_t)i * DMc, (long)NLc * DMc,
        o, DMc, (long)SZ_X, ROWS, DMc, DIc);
    // x = 3x + o0 + o1
    combine_k<<<(int)(SZ_X / 256), 256, 0, stream>>>(x, o);
    // MLP over L axis
    mlp_norm_k<<<Bb * DMc, 256, 0, stream>>>(
        x, lin_norm_w + (size_t)i * Ls, lin_norm_b + (size_t)i * Ls, hn, i == 0 ? 1 : 0);
    gemm_f32<1><<<dim3(HIDc / 64, (Bb * DMc) / 64, 1), 256, 0, stream>>>(
        hn, Ls, 0, lin_W1 + (size_t)i * HIDc * Ls, Ls, 0,
        lin_b1 + (size_t)i * HIDc, 0, h1, HIDc, 0, Bb * DMc, HIDc, Ls);
    gemm_f32<0><<<dim3(Ls / 64, (Bb * DMc) / 64, 1), 256, 0, stream>>>(
        h1, HIDc, 0, lin_W2 + (size_t)i * Ls * HIDc, HIDc, 0,
        lin_b2 + (size_t)i * Ls, 0, h2, Ls, 0, Bb * DMc, Ls, HIDc);
    addback_k<<<(int)(SZ_X / 256), 256, 0, stream>>>(x, h2);
  }
  // final LN(x + resid)
  ln_final_k<<<ROWS, 256, 0, stream>>>(x, resid, normf_g, normf_b, out);
}

// Round 2
// 1428.721 us; speedup vs baseline: 1.6322x; 1.6322x over previous
//
#include <hip/hip_runtime.h>
#include <cstddef>

// ---- problem constants ----
constexpr int Bb = 4, Ls = 512, Vv = 256, DMc = 256, DIc = 512, Nn = 16;
constexpr int DTRc = 16, NLc = 4, HIDc = 512;
constexpr int ROWS = Bb * Ls;  // 2048

// chunked-scan constants
constexpr int CHUNK = 32, NCH = Ls / CHUNK;          // 16 chunks
constexpr int NCHAIN = 2 * Bb * DIc * Nn;            // 65536 chains (incl dir)

// per-direction buffer sizes (floats)
constexpr size_t SZ_X  = (size_t)ROWS * DMc;      // 524288
constexpr size_t SZ_XR = (size_t)ROWS * 2 * DIc;  // 2097152
constexpr size_t SZ_XC = (size_t)ROWS * DIc;      // 1048576
constexpr size_t SZ_XD = (size_t)ROWS * 48;       // 98304

// workspace layout (float offsets)
constexpr size_t X_OFF    = 0;
constexpr size_t RES_OFF  = SZ_X;
constexpr size_t O_OFF    = 2 * SZ_X;              // 2 dirs
constexpr size_t XLN_OFF  = 4 * SZ_X;              // 2 dirs
constexpr size_t XR_OFF   = 6 * SZ_X;              // 2 dirs x SZ_XR
constexpr size_t XC_OFF   = XR_OFF + 2 * SZ_XR;    // 2 dirs
constexpr size_t XDBL_OFF = XC_OFF + 2 * SZ_XC;    // 2 dirs
constexpr size_t DELTA_OFF= XDBL_OFF + 2 * SZ_XD;  // 2 dirs
constexpr size_t YG_OFF   = DELTA_OFF + 2 * SZ_XC; // 2 dirs
// MLP buffers alias XR region (dead after scan epilogue)
constexpr size_t HN_OFF = XR_OFF;
constexpr size_t H1_OFF = XR_OFF + SZ_X;
constexpr size_t H2_OFF = XR_OFF + 2 * SZ_X;
// chunked-scan scratch: aliases [O, XLN) = 4*SZ_X floats = exactly NCH*NCHAIN float2.
// Dead region during scan phase (o written after scan, xln consumed before).
constexpr size_t P_OFF = O_OFF;

// ---------------- generic f32 GEMM: C = A @ W^T + bias, act ----------------
// A: M x K (lda), W: N x K (ldw), C: M x N (ldc). z-batched via strides.
// ACT: 0=none, 1=relu, 2=softplus
template <int ACT>
__global__ __launch_bounds__(256) void gemm_f32(
    const float* __restrict__ A, int lda, long sA,
    const float* __restrict__ W, int ldw, long sW,
    const float* __restrict__ bias, long sB,
    float* __restrict__ C, int ldc, long sC,
    int M, int N, int K) {
  int z = blockIdx.z;
  A += (size_t)z * sA;
  W += (size_t)z * sW;
  if (bias) bias += (size_t)z * sB;
  C += (size_t)z * sC;

  __shared__ float As[64][17];
  __shared__ float Ws[64][17];
  int tid = threadIdx.x;
  int m0 = blockIdx.y * 64, n0 = blockIdx.x * 64;
  int tx = tid & 15, ty = tid >> 4;
  int lr = tid >> 2;         // 0..63 tile row to load
  int lk = (tid & 3) * 4;    // k offset within 16-chunk

  float acc[4][4] = {};
  for (int k0 = 0; k0 < K; k0 += 16) {
    {
      int r = m0 + lr;
      float4 v = make_float4(0.f, 0.f, 0.f, 0.f);
      if (r < M) v = *reinterpret_cast<const float4*>(A + (size_t)r * lda + k0 + lk);
      As[lr][lk + 0] = v.x; As[lr][lk + 1] = v.y; As[lr][lk + 2] = v.z; As[lr][lk + 3] = v.w;
      int rn = n0 + lr;
      float4 w = make_float4(0.f, 0.f, 0.f, 0.f);
      if (rn < N) w = *reinterpret_cast<const float4*>(W + (size_t)rn * ldw + k0 + lk);
      Ws[lr][lk + 0] = w.x; Ws[lr][lk + 1] = w.y; Ws[lr][lk + 2] = w.z; Ws[lr][lk + 3] = w.w;
    }
    __syncthreads();
#pragma unroll
    for (int kk = 0; kk < 16; kk++) {
      float a[4], b[4];
#pragma unroll
      for (int i = 0; i < 4; i++) a[i] = As[ty * 4 + i][kk];
#pragma unroll
      for (int j = 0; j < 4; j++) b[j] = Ws[tx * 4 + j][kk];
#pragma unroll
      for (int i = 0; i < 4; i++)
#pragma unroll
        for (int j = 0; j < 4; j++) acc[i][j] += a[i] * b[j];
    }
    __syncthreads();
  }
#pragma unroll
  for (int i = 0; i < 4; i++) {
    int row = m0 + ty * 4 + i;
    if (row >= M) continue;
#pragma unroll
    for (int j = 0; j < 4; j++) {
      int col = n0 + tx * 4 + j;
      if (col >= N) continue;
      float v = acc[i][j] + (bias ? bias[col] : 0.f);
      if (ACT == 1) v = fmaxf(v, 0.f);
      if (ACT == 2) v = fmaxf(v, 0.f) + log1pf(__expf(-fabsf(v)));
      C[(size_t)row * ldc + col] = v;
    }
  }
}

// ---------------- block reduce (256 threads, 2 values) ----------------
__device__ __forceinline__ void block_reduce_2(float& a, float& b, float* sa, float* sb) {
#pragma unroll
  for (int m = 32; m >= 1; m >>= 1) {
    a += __shfl_xor(a, m);
    b += __shfl_xor(b, m);
  }
  int wid = threadIdx.x >> 6, lane = threadIdx.x & 63;
  if (lane == 0) { sa[wid] = a; sb[wid] = b; }
  __syncthreads();
  a = sa[0] + sa[1] + sa[2] + sa[3];
  b = sb[0] + sb[1] + sb[2] + sb[3];
}

// ---------------- LN over DM (z = dir) ----------------
__global__ __launch_bounds__(256) void ln_dm_k(
    const float* __restrict__ x, const float* __restrict__ g,
    const float* __restrict__ bt, float* __restrict__ xln, int layer) {
  int dir = blockIdx.z;
  g += (size_t)(dir * NLc + layer) * DMc;
  bt += (size_t)(dir * NLc + layer) * DMc;
  float* out = xln + (size_t)dir * SZ_X;
  int row = blockIdx.x, t = threadIdx.x;
  float v = x[(size_t)row * DMc + t];
  float a = v, q = v * v;
  __shared__ float sa[4], sb[4];
  block_reduce_2(a, q, sa, sb);
  float mu = a * (1.f / DMc);
  float var = q * (1.f / DMc) - mu * mu;
  float inv = rsqrtf(var + 1e-5f);
  out[(size_t)row * DMc + t] = (v - mu) * inv * g[t] + bt[t];
}

// ---------------- final LN(x + resid) ----------------
__global__ __launch_bounds__(256) void ln_final_k(
    const float* __restrict__ x, const float* __restrict__ resid,
    const float* __restrict__ g, const float* __restrict__ bt,
    float* __restrict__ out) {
  int row = blockIdx.x, t = threadIdx.x;
  float v = x[(size_t)row * DMc + t] + resid[(size_t)row * DMc + t];
  float a = v, q = v * v;
  __shared__ float sa[4], sb[4];
  block_reduce_2(a, q, sa, sb);
  float mu = a * (1.f / DMc);
  float var = q * (1.f / DMc) - mu * mu;
  float inv = rsqrtf(var + 1e-5f);
  out[(size_t)row * DMc + t] = (v - mu) * inv * g[t] + bt[t];
}

// ---------------- causal depthwise conv (DC=4) + SiLU (z = dir) ----------------
__global__ __launch_bounds__(256) void conv_silu_k(
    const float* __restrict__ xr, const float* __restrict__ cw,
    const float* __restrict__ cb, float* __restrict__ xc, int layer) {
  int dir = blockIdx.z;
  const float* xin = xr + (size_t)dir * SZ_XR;  // cols 0..511 of 1024-wide rows
  const float* w = cw + (size_t)(dir * NLc + layer) * DIc * 4;
  const float* bb = cb + (size_t)(dir * NLc + layer) * DIc;
  float* out = xc + (size_t)dir * SZ_XC;
  int gid = blockIdx.x * 256 + threadIdx.x;  // < ROWS*DI
  int d = gid & 511, row = gid >> 9, l = row & 511;
  float w0 = w[d * 4 + 0], w1 = w[d * 4 + 1], w2 = w[d * 4 + 2], w3 = w[d * 4 + 3];
  float acc = bb[d];
  if (dir == 0) {  // out[l] = sum_k w[k]*x[l-3+k]
    acc += w3 * xin[(size_t)row * 1024 + d];
    if (l >= 1) acc += w2 * xin[(size_t)(row - 1) * 1024 + d];
    if (l >= 2) acc += w1 * xin[(size_t)(row - 2) * 1024 + d];
    if (l >= 3) acc += w0 * xin[(size_t)(row - 3) * 1024 + d];
  } else {         // reversed seq: out[l] = sum_k w[k]*x[l+3-k]
    acc += w3 * xin[(size_t)row * 1024 + d];
    if (l + 1 < Ls) acc += w2 * xin[(size_t)(row + 1) * 1024 + d];
    if (l + 2 < Ls) acc += w1 * xin[(size_t)(row + 2) * 1024 + d];
    if (l + 3 < Ls) acc += w0 * xin[(size_t)(row + 3) * 1024 + d];
  }
  out[(size_t)row * DIc + d] = acc * (1.f / (1.f + __expf(-acc)));
}

// ---------------- chunked selective scan ----------------
// pass 1: per (chain, chunk) compute transfer (a = prod dA, c = local state)
// thread map: t = dsub*16 + n; block = (b, dtile, chunk); z = dir
__global__ __launch_bounds__(256) void scan_p1(
    const float* __restrict__ delta, const float* __restrict__ xc,
    const float* __restrict__ xdbl, const float* __restrict__ A_log,
    float2* __restrict__ P, int layer) {
  int dir = blockIdx.z;
  const float* dlt = delta + (size_t)dir * SZ_XC;
  const float* u   = xc + (size_t)dir * SZ_XC;
  const float* xd  = xdbl + (size_t)dir * SZ_XD;
  int t = threadIdx.x;
  int n = t & 15, dsub = t >> 4;
  int bx = blockIdx.x;
  int c = bx & 15, dtile = (bx >> 4) & 31, b = bx >> 9;
  int d = dtile * 16 + dsub;
  float Adn = -__expf(A_log[((size_t)(dir * NLc + layer) * DIc + d) * Nn + n]);
  int l0 = dir ? (Ls - 1) : 0;
  int step = dir ? -1 : 1;
  size_t base = (size_t)b * Ls;
  float a = 1.f, s = 0.f;
#pragma unroll 4
  for (int j = 0; j < CHUNK; j++) {
    int l = l0 + (c * CHUNK + j) * step;
    size_t idx = base + l;
    float dv = dlt[idx * DIc + d];
    float uv = u[idx * DIc + d];
    float bm = xd[idx * 48 + 16 + n];
    float dA = __expf(dv * Adn);
    a *= dA;
    s = dA * s + dv * bm * uv;
  }
  int ch = ((dir * Bb + b) * DIc + d) * Nn + n;
  P[(size_t)c * NCHAIN + ch] = make_float2(a, s);
}

// pass 2: per chain, combine the 16 chunk transfers; overwrite .x with the
// chunk's INITIAL state (state entering that chunk).
__global__ __launch_bounds__(256) void scan_mid(float2* __restrict__ P) {
  int ch = blockIdx.x * 256 + threadIdx.x;
  float s = 0.f;
#pragma unroll
  for (int c = 0; c < NCH; c++) {
    float2 ac = P[(size_t)c * NCHAIN + ch];
    P[(size_t)c * NCHAIN + ch].x = s;
    s = ac.x * s + ac.y;
  }
}

// pass 3: re-scan each chunk from its init state; n-reduce, gate, write yg
__global__ __launch_bounds__(256) void scan_p2(
    const float* __restrict__ delta, const float* __restrict__ xc,
    const float* __restrict__ xdbl, const float* __restrict__ xr,
    const float* __restrict__ A_log, const float* __restrict__ Dp,
    const float2* __restrict__ P, float* __restrict__ yg, int layer) {
  int dir = blockIdx.z;
  const float* dlt = delta + (size_t)dir * SZ_XC;
  const float* u   = xc + (size_t)dir * SZ_XC;
  const float* xd  = xdbl + (size_t)dir * SZ_XD;
  const float* res = xr + (size_t)dir * SZ_XR;
  float* out = yg + (size_t)dir * SZ_XC;
  int t = threadIdx.x;
  int n = t & 15, dsub = t >> 4;
  int bx = blockIdx.x;
  int c = bx & 15, dtile = (bx >> 4) & 31, b = bx >> 9;
  int d = dtile * 16 + dsub;
  float Adn = -__expf(A_log[((size_t)(dir * NLc + layer) * DIc + d) * Nn + n]);
  float Dd = Dp[(size_t)(dir * NLc + layer) * DIc + d];
  int l0 = dir ? (Ls - 1) : 0;
  int step = dir ? -1 : 1;
  size_t base = (size_t)b * Ls;
  int ch = ((dir * Bb + b) * DIc + d) * Nn + n;
  float s = P[(size_t)c * NCHAIN + ch].x;
#pragma unroll 4
  for (int j = 0; j < CHUNK; j++) {
    int l = l0 + (c * CHUNK + j) * step;
    size_t idx = base + l;
    float dv = dlt[idx * DIc + d];
    float uv = u[idx * DIc + d];
    float bm = xd[idx * 48 + 16 + n];
    float cm = xd[idx * 48 + 32 + n];
    float dA = __expf(dv * Adn);
    s = dA * s + dv * bm * uv;
    float v = s * cm;
    v += __shfl_xor(v, 1); v += __shfl_xor(v, 2);
    v += __shfl_xor(v, 4); v += __shfl_xor(v, 8);
    if (n == 0) {
      float rv = res[idx * 1024 + DIc + d];
      float sig = 1.f / (1.f + __expf(-rv));
      out[idx * DIc + d] = (v + uv * Dd) * (rv * sig);
    }
  }
}

// ---------------- combine: x = 3x + o0 + o1 ----------------
__global__ __launch_bounds__(256) void combine_k(float* __restrict__ x,
                                                 const float* __restrict__ o) {
  size_t g = (size_t)blockIdx.x * 256 + threadIdx.x;
  x[g] = 3.f * x[g] + o[g] + o[g + SZ_X];
}

// ---------------- copy ----------------
__global__ __launch_bounds__(256) void copy_k(const float* __restrict__ a,
                                              float* __restrict__ b) {
  size_t g = (size_t)blockIdx.x * 256 + threadIdx.x;
  b[g] = a[g];
}

// ---------------- MLP norm over L (transposed read); use_ln ? LN : RMS ----------------
__global__ __launch_bounds__(256) void mlp_norm_k(
    const float* __restrict__ x, const float* __restrict__ w,
    const float* __restrict__ bb, float* __restrict__ hn, int use_ln) {
  int r = blockIdx.x;           // b*DM + m
  int b = r >> 8, m = r & 255;
  int t = threadIdx.x;
  const float* xb = x + (size_t)b * Ls * DMc + m;
  float v0 = xb[(size_t)t * DMc];
  float v1 = xb[(size_t)(t + 256) * DMc];
  float a = v0 + v1, q = v0 * v0 + v1 * v1;
  __shared__ float sa[4], sb[4];
  block_reduce_2(a, q, sa, sb);
  float mu = use_ln ? a * (1.f / Ls) : 0.f;
  float var = q * (1.f / Ls) - mu * mu;
  float inv = rsqrtf(var + 1e-5f);
  float* o = hn + (size_t)r * Ls;
  o[t] = (v0 - mu) * inv * w[t] + (use_ln ? bb[t] : 0.f);
  o[t + 256] = (v1 - mu) * inv * w[t + 256] + (use_ln ? bb[t + 256] : 0.f);
}

// ---------------- add-back: x[b,l,m] += h2[(b*DM+m)*L + l] ----------------
__global__ __launch_bounds__(256) void addback_k(float* __restrict__ x,
                                                 const float* __restrict__ h2) {
  size_t g = (size_t)blockIdx.x * 256 + threadIdx.x;
  int m = (int)(g & 255);
  int r = (int)(g >> 8);
  int l = r & 511, b = r >> 9;
  x[g] += h2[((size_t)(b * DMc + m)) * Ls + l];
}

// =======================================================================
extern "C" void kernel_launch(void* const* d_in, const int* in_sizes, int n_in,
                              void* d_out, int out_size, void* d_ws, size_t ws_size,
                              hipStream_t stream) {
  const float* input_ids = (const float*)d_in[0];
  const float* emb_W     = (const float*)d_in[1];
  const float* emb_b     = (const float*)d_in[2];
  const float* ln_g      = (const float*)d_in[3];
  const float* ln_b      = (const float*)d_in[4];
  const float* inproj_W  = (const float*)d_in[5];
  const float* inproj_b  = (const float*)d_in[6];
  const float* conv_w    = (const float*)d_in[7];
  const float* conv_b    = (const float*)d_in[8];
  const float* xproj_W   = (const float*)d_in[9];
  const float* dtproj_W  = (const float*)d_in[10];
  const float* dtproj_b  = (const float*)d_in[11];
  const float* outproj_W = (const float*)d_in[12];
  const float* outproj_b = (const float*)d_in[13];
  const float* A_log     = (const float*)d_in[14];
  const float* Dp        = (const float*)d_in[15];
  const float* lin_norm_w= (const float*)d_in[16];
  const float* lin_norm_b= (const float*)d_in[17];
  const float* lin_W1    = (const float*)d_in[18];
  const float* lin_b1    = (const float*)d_in[19];
  const float* lin_W2    = (const float*)d_in[20];
  const float* lin_b2    = (const float*)d_in[21];
  const float* normf_g   = (const float*)d_in[22];
  const float* normf_b   = (const float*)d_in[23];
  float* out = (float*)d_out;

  float* ws    = (float*)d_ws;
  float* x     = ws + X_OFF;
  float* resid = ws + RES_OFF;
  float* o     = ws + O_OFF;
  float* xln   = ws + XLN_OFF;
  float* xr    = ws + XR_OFF;
  float* xc    = ws + XC_OFF;
  float* xdbl  = ws + XDBL_OFF;
  float* delta = ws + DELTA_OFF;
  float* yg    = ws + YG_OFF;
  float* hn    = ws + HN_OFF;
  float* h1    = ws + H1_OFF;
  float* h2    = ws + H2_OFF;
  float2* P    = (float2*)(ws + P_OFF);  // aliases [o, xln) — dead during scan

  // 1. embedding: x = ids @ emb_W^T + emb_b   (2048x256x256)
  gemm_f32<0><<<dim3(DMc / 64, ROWS / 64, 1), 256, 0, stream>>>(
      input_ids, Vv, 0, emb_W, Vv, 0, emb_b, 0, x, DMc, 0, ROWS, DMc, Vv);
  copy_k<<<(int)(SZ_X / 256), 256, 0, stream>>>(x, resid);

  for (int i = 0; i < NLc; i++) {
    // LN per dir
    ln_dm_k<<<dim3(ROWS, 1, 2), 256, 0, stream>>>(x, ln_g, ln_b, xln, i);
    // inproj: 2048 x 1024 x 256 (both dirs)
    gemm_f32<0><<<dim3(16, ROWS / 64, 2), 256, 0, stream>>>(
        xln, DMc, (long)SZ_X,
        inproj_W + (size_t)i * 2 * DIc * DMc, DMc, (long)NLc * 2 * DIc * DMc,
        inproj_b + (size_t)i * 2 * DIc, (long)NLc * 2 * DIc,
        xr, 2 * DIc, (long)SZ_XR, ROWS, 2 * DIc, DMc);
    // depthwise causal conv + SiLU
    conv_silu_k<<<dim3(ROWS * DIc / 256, 1, 2), 256, 0, stream>>>(xr, conv_w, conv_b, xc, i);
    // xproj: 2048 x 48 x 512
    gemm_f32<0><<<dim3(1, ROWS / 64, 2), 256, 0, stream>>>(
        xc, DIc, (long)SZ_XC,
        xproj_W + (size_t)i * 48 * DIc, DIc, (long)NLc * 48 * DIc,
        nullptr, 0, xdbl, 48, (long)SZ_XD, ROWS, 48, DIc);
    // dtproj + softplus: 2048 x 512 x 16
    gemm_f32<2><<<dim3(8, ROWS / 64, 2), 256, 0, stream>>>(
        xdbl, 48, (long)SZ_XD,
        dtproj_W + (size_t)i * DIc * DTRc, DTRc, (long)NLc * DIc * DTRc,
        dtproj_b + (size_t)i * DIc, (long)NLc * DIc,
        delta, DIc, (long)SZ_XC, ROWS, DIc, DTRc);
    // chunked selective scan + gate (3 passes)
    scan_p1<<<dim3(Bb * 32 * NCH, 1, 2), 256, 0, stream>>>(
        delta, xc, xdbl, A_log, P, i);
    scan_mid<<<dim3(NCHAIN / 256, 1, 1), 256, 0, stream>>>(P);
    scan_p2<<<dim3(Bb * 32 * NCH, 1, 2), 256, 0, stream>>>(
        delta, xc, xdbl, xr, A_log, Dp, P, yg, i);
    // outproj: 2048 x 256 x 512
    gemm_f32<0><<<dim3(4, ROWS / 64, 2), 256, 0, stream>>>(
        yg, DIc, (long)SZ_XC,
        outproj_W + (size_t)i * DMc * DIc, DIc, (long)NLc * DMc * DIc,
        outproj_b + (size_t)i * DMc, (long)NLc * DMc,
        o, DMc, (long)SZ_X, ROWS, DMc, DIc);
    // x = 3x + o0 + o1
    combine_k<<<(int)(SZ_X / 256), 256, 0, stream>>>(x, o);
    // MLP over L axis
    mlp_norm_k<<<Bb * DMc, 256, 0, stream>>>(
        x, lin_norm_w + (size_t)i * Ls, lin_norm_b + (size_t)i * Ls, hn, i == 0 ? 1 : 0);
    gemm_f32<1><<<dim3(HIDc / 64, (Bb * DMc) / 64, 1), 256, 0, stream>>>(
        hn, Ls, 0, lin_W1 + (size_t)i * HIDc * Ls, Ls, 0,
        lin_b1 + (size_t)i * HIDc, 0, h1, HIDc, 0, Bb * DMc, HIDc, Ls);
    gemm_f32<0><<<dim3(Ls / 64, (Bb * DMc) / 64, 1), 256, 0, stream>>>(
        h1, HIDc, 0, lin_W2 + (size_t)i * Ls * HIDc, HIDc, 0,
        lin_b2 + (size_t)i * Ls, 0, h2, Ls, 0, Bb * DMc, Ls, HIDc);
    addback_k<<<(int)(SZ_X / 256), 256, 0, stream>>>(x, h2);
  }
  // final LN(x + resid)
  ln_final_k<<<ROWS, 256, 0, stream>>>(x, resid, normf_g, normf_b, out);
}

// Round 3
// 676.498 us; speedup vs baseline: 3.4471x; 2.1119x over previous
//
#include <hip/hip_runtime.h>
#include <hip/hip_bf16.h>
#include <cstddef>

// ---- problem constants ----
constexpr int Bb = 4, Ls = 512, Vv = 256, DMc = 256, DIc = 512, Nn = 16;
constexpr int DTRc = 16, NLc = 4, HIDc = 512;
constexpr int ROWS = Bb * Ls;  // 2048

// chunked-scan constants
constexpr int CHUNK = 32, NCH = Ls / CHUNK;          // 16 chunks
constexpr int NCHAIN = 2 * Bb * DIc * Nn;            // 65536 chains (incl dir)

// per-direction buffer sizes (floats)
constexpr size_t SZ_X  = (size_t)ROWS * DMc;      // 524288
constexpr size_t SZ_XR = (size_t)ROWS * 2 * DIc;  // 2097152
constexpr size_t SZ_XC = (size_t)ROWS * DIc;      // 1048576
constexpr size_t SZ_XD = (size_t)ROWS * 48;       // 98304

// workspace layout (float offsets)
constexpr size_t X_OFF    = 0;
constexpr size_t RES_OFF  = SZ_X;
constexpr size_t O_OFF    = 2 * SZ_X;              // 2 dirs (o f32)
constexpr size_t XLN_OFF  = 4 * SZ_X;              // (f32 region reused for bf16)
constexpr size_t XR_OFF   = 6 * SZ_X;              // 2 dirs x SZ_XR
constexpr size_t XC_OFF   = XR_OFF + 2 * SZ_XR;    // 2 dirs
constexpr size_t XDBL_OFF = XC_OFF + 2 * SZ_XC;    // 2 dirs (f32)
constexpr size_t DELTA_OFF= XDBL_OFF + 2 * SZ_XD;  // 2 dirs
constexpr size_t YG_OFF   = DELTA_OFF + 2 * SZ_XC; // region reused for bf16 bufs
constexpr size_t WS_END0  = YG_OFF + 2 * SZ_XC;    // 13,828,096 floats

// scan transfer scratch P aliases [O_OFF, O_OFF+4*SZ_X) (o + xln f32 regions;
// both dead during the scan phase)
constexpr size_t P_OFF = O_OFF;

// bf16 activation buffers aliased into dead f32 regions (offsets in floats)
constexpr size_t XLNB_OFF  = XLN_OFF;                 // 2*SZ_X bf16 (524288 fl)
constexpr size_t XDBLB_OFF = XLN_OFF + 524288;        // 2*SZ_XD bf16 (98304 fl)
constexpr size_t XCB_OFF   = YG_OFF;                  // 2*SZ_XC bf16 (1048576 fl)
constexpr size_t YGB_OFF   = YG_OFF + 1048576;        // 2*SZ_XC bf16 (1048576 fl)
// MLP-phase aliases inside XR region (xr f32 dead after scan)
constexpr size_t HNB_OFF = XR_OFF;                    // SZ_X bf16 (262144 fl)
constexpr size_t H1F_OFF = XR_OFF + 262144;           // SZ_X f32
constexpr size_t H1B_OFF = XR_OFF + 786432;           // SZ_X bf16 (262144 fl)
constexpr size_t H2_OFF  = XR_OFF + 1048576;          // SZ_X f32
// embedding-phase aliases inside XR region (pre-layer only)
constexpr size_t IDSB_OFF = XR_OFF;                   // ROWS*Vv bf16 (262144 fl)
constexpr size_t WEMB_OFF = XR_OFF + 262144;          // DMc*Vv bf16 (32768 fl)
// persistent bf16 weights (new region)
constexpr size_t WBIN_OFF  = WS_END0;                 // 2*4*1024*256 bf16
constexpr size_t WBX_OFF   = WBIN_OFF + 1048576;      // 2*4*48*512 bf16
constexpr size_t WBDT_OFF  = WBX_OFF + 98304;         // 2*4*512*16 bf16
constexpr size_t WBOUT_OFF = WBDT_OFF + 32768;        // 2*4*256*512 bf16
constexpr size_t WB1_OFF   = WBOUT_OFF + 524288;      // 4*512*512 bf16
constexpr size_t WB2_OFF   = WB1_OFF + 524288;        // 4*512*512 bf16

typedef __attribute__((ext_vector_type(8))) short bfrag8;
typedef __attribute__((ext_vector_type(4))) float f32x4;

// ---------------- fused f32->bf16 cast, 8 segments, one launch ----------------
struct CastSeg { const float* s; __hip_bfloat16* d; int n4; };
struct CastArgs { CastSeg seg[8]; };
__global__ __launch_bounds__(256) void cast8_k(CastArgs a) {
  CastSeg sg = a.seg[blockIdx.y];
  for (int i = blockIdx.x * 256 + threadIdx.x; i < sg.n4; i += gridDim.x * 256) {
    float4 v = reinterpret_cast<const float4*>(sg.s)[i];
    __hip_bfloat16 h0 = __float2bfloat16(v.x), h1 = __float2bfloat16(v.y);
    __hip_bfloat16 h2 = __float2bfloat16(v.z), h3 = __float2bfloat16(v.w);
    ushort4 u;
    u.x = *reinterpret_cast<unsigned short*>(&h0);
    u.y = *reinterpret_cast<unsigned short*>(&h1);
    u.z = *reinterpret_cast<unsigned short*>(&h2);
    u.w = *reinterpret_cast<unsigned short*>(&h3);
    *reinterpret_cast<ushort4*>(sg.d + (size_t)i * 4) = u;
  }
}

// ---------------- bf16 MFMA GEMM: C = A @ W^T + bias, act ----------------
// A: MxK bf16 (lda), W: NxK bf16 (ldw), C: MxN f32 (ldc), optional bf16 copy.
// 64x64 block tile, 4 waves (2x2), 32x32 wave tile, BK=32, mfma_f32_16x16x32_bf16.
// M must be multiple of 64; N,K arbitrary-ish (K multiple of 8; N bounds-checked).
template <int ACT, bool BF16OUT>
__global__ __launch_bounds__(256) void gemm_bf(
    const __hip_bfloat16* __restrict__ A, int lda, long sA,
    const __hip_bfloat16* __restrict__ W, int ldw, long sW,
    const float* __restrict__ bias, long sB,
    float* __restrict__ C, __hip_bfloat16* __restrict__ Cb, int ldc, long sC,
    int M, int N, int K) {
  int z = blockIdx.z;
  A += (size_t)z * sA;
  W += (size_t)z * sW;
  if (bias) bias += (size_t)z * sB;
  C += (size_t)z * sC;
  if (BF16OUT) Cb += (size_t)z * sC;

  constexpr int LDT = 40;  // padded LDS row stride (bf16) -> <=2-way bank conflict
  __shared__ unsigned short As[64 * LDT];
  __shared__ unsigned short Wt[64 * LDT];
  int tid = threadIdx.x;
  int l = tid & 63, w = tid >> 6;
  int wr = w >> 1, wc = w & 1;
  int m0 = blockIdx.y * 64, n0 = blockIdx.x * 64;
  int lrow = l & 15, lk = (l >> 4) * 8;

  f32x4 zero = {0.f, 0.f, 0.f, 0.f};
  f32x4 acc[2][2];
  acc[0][0] = zero; acc[0][1] = zero; acc[1][0] = zero; acc[1][1] = zero;

  // staging map: 64 rows x 4 k-segments of 8 bf16 = 256 segments, 1/thread
  int sr = tid >> 2, sk = (tid & 3) * 8;

  for (int k0 = 0; k0 < K; k0 += 32) {
    uint4 va = make_uint4(0, 0, 0, 0), vw = make_uint4(0, 0, 0, 0);
    if (k0 + sk < K) {
      va = *reinterpret_cast<const uint4*>(A + (size_t)(m0 + sr) * lda + k0 + sk);
      int rn = n0 + sr; if (rn >= N) rn = N - 1;
      vw = *reinterpret_cast<const uint4*>(W + (size_t)rn * ldw + k0 + sk);
    }
    *reinterpret_cast<uint4*>(&As[sr * LDT + sk]) = va;
    *reinterpret_cast<uint4*>(&Wt[sr * LDT + sk]) = vw;
    __syncthreads();
    bfrag8 af[2], bf[2];
#pragma unroll
    for (int f = 0; f < 2; f++) {
      af[f] = *reinterpret_cast<const bfrag8*>(&As[(wr * 32 + f * 16 + lrow) * LDT + lk]);
      bf[f] = *reinterpret_cast<const bfrag8*>(&Wt[(wc * 32 + f * 16 + lrow) * LDT + lk]);
    }
#pragma unroll
    for (int fr = 0; fr < 2; fr++)
#pragma unroll
      for (int fc = 0; fc < 2; fc++)
        acc[fr][fc] = __builtin_amdgcn_mfma_f32_16x16x32_bf16(af[fr], bf[fc], acc[fr][fc], 0, 0, 0);
    __syncthreads();
  }

  // epilogue: C/D layout col = lane&15, row = (lane>>4)*4 + j   [m89-verified]
#pragma unroll
  for (int fr = 0; fr < 2; fr++) {
    int row = m0 + wr * 32 + fr * 16 + (l >> 4) * 4;
#pragma unroll
    for (int fc = 0; fc < 2; fc++) {
      int col = n0 + wc * 32 + fc * 16 + (l & 15);
      if (col < N) {
        float bv = bias ? bias[col] : 0.f;
#pragma unroll
        for (int j = 0; j < 4; j++) {
          float v = acc[fr][fc][j] + bv;
          if (ACT == 1) v = fmaxf(v, 0.f);
          if (ACT == 2) v = fmaxf(v, 0.f) + log1pf(__expf(-fabsf(v)));
          C[(size_t)(row + j) * ldc + col] = v;
          if (BF16OUT) Cb[(size_t)(row + j) * ldc + col] = __float2bfloat16(v);
        }
      }
    }
  }
}

// ---------------- block reduce (256 threads, 2 values) ----------------
__device__ __forceinline__ void block_reduce_2(float& a, float& b, float* sa, float* sb) {
#pragma unroll
  for (int m = 32; m >= 1; m >>= 1) {
    a += __shfl_xor(a, m);
    b += __shfl_xor(b, m);
  }
  int wid = threadIdx.x >> 6, lane = threadIdx.x & 63;
  if (lane == 0) { sa[wid] = a; sb[wid] = b; }
  __syncthreads();
  a = sa[0] + sa[1] + sa[2] + sa[3];
  b = sb[0] + sb[1] + sb[2] + sb[3];
}

// ---------------- LN over DM (z = dir) -> bf16 ----------------
__global__ __launch_bounds__(256) void ln_dm_k(
    const float* __restrict__ x, const float* __restrict__ g,
    const float* __restrict__ bt, __hip_bfloat16* __restrict__ xlnb, int layer) {
  int dir = blockIdx.z;
  g += (size_t)(dir * NLc + layer) * DMc;
  bt += (size_t)(dir * NLc + layer) * DMc;
  __hip_bfloat16* out = xlnb + (size_t)dir * SZ_X;
  int row = blockIdx.x, t = threadIdx.x;
  float v = x[(size_t)row * DMc + t];
  float a = v, q = v * v;
  __shared__ float sa[4], sb[4];
  block_reduce_2(a, q, sa, sb);
  float mu = a * (1.f / DMc);
  float var = q * (1.f / DMc) - mu * mu;
  float inv = rsqrtf(var + 1e-5f);
  out[(size_t)row * DMc + t] = __float2bfloat16((v - mu) * inv * g[t] + bt[t]);
}

// ---------------- final LN(x + resid) ----------------
__global__ __launch_bounds__(256) void ln_final_k(
    const float* __restrict__ x, const float* __restrict__ resid,
    const float* __restrict__ g, const float* __restrict__ bt,
    float* __restrict__ out) {
  int row = blockIdx.x, t = threadIdx.x;
  float v = x[(size_t)row * DMc + t] + resid[(size_t)row * DMc + t];
  float a = v, q = v * v;
  __shared__ float sa[4], sb[4];
  block_reduce_2(a, q, sa, sb);
  float mu = a * (1.f / DMc);
  float var = q * (1.f / DMc) - mu * mu;
  float inv = rsqrtf(var + 1e-5f);
  out[(size_t)row * DMc + t] = (v - mu) * inv * g[t] + bt[t];
}

// ---------------- causal depthwise conv (DC=4) + SiLU (z = dir) ----------------
__global__ __launch_bounds__(256) void conv_silu_k(
    const float* __restrict__ xr, const float* __restrict__ cw,
    const float* __restrict__ cb, float* __restrict__ xc,
    __hip_bfloat16* __restrict__ xcb, int layer) {
  int dir = blockIdx.z;
  const float* xin = xr + (size_t)dir * SZ_XR;
  const float* w = cw + (size_t)(dir * NLc + layer) * DIc * 4;
  const float* bb = cb + (size_t)(dir * NLc + layer) * DIc;
  float* out = xc + (size_t)dir * SZ_XC;
  __hip_bfloat16* outb = xcb + (size_t)dir * SZ_XC;
  int gid = blockIdx.x * 256 + threadIdx.x;
  int d = gid & 511, row = gid >> 9, l = row & 511;
  float w0 = w[d * 4 + 0], w1 = w[d * 4 + 1], w2 = w[d * 4 + 2], w3 = w[d * 4 + 3];
  float acc = bb[d];
  if (dir == 0) {
    acc += w3 * xin[(size_t)row * 1024 + d];
    if (l >= 1) acc += w2 * xin[(size_t)(row - 1) * 1024 + d];
    if (l >= 2) acc += w1 * xin[(size_t)(row - 2) * 1024 + d];
    if (l >= 3) acc += w0 * xin[(size_t)(row - 3) * 1024 + d];
  } else {
    acc += w3 * xin[(size_t)row * 1024 + d];
    if (l + 1 < Ls) acc += w2 * xin[(size_t)(row + 1) * 1024 + d];
    if (l + 2 < Ls) acc += w1 * xin[(size_t)(row + 2) * 1024 + d];
    if (l + 3 < Ls) acc += w0 * xin[(size_t)(row + 3) * 1024 + d];
  }
  float r = acc * (1.f / (1.f + __expf(-acc)));
  out[(size_t)row * DIc + d] = r;
  outb[(size_t)row * DIc + d] = __float2bfloat16(r);
}

// ---------------- chunked selective scan ----------------
__global__ __launch_bounds__(256) void scan_p1(
    const float* __restrict__ delta, const float* __restrict__ xc,
    const float* __restrict__ xdbl, const float* __restrict__ A_log,
    float2* __restrict__ P, int layer) {
  int dir = blockIdx.z;
  const float* dlt = delta + (size_t)dir * SZ_XC;
  const float* u   = xc + (size_t)dir * SZ_XC;
  const float* xd  = xdbl + (size_t)dir * SZ_XD;
  int t = threadIdx.x;
  int n = t & 15, dsub = t >> 4;
  int bx = blockIdx.x;
  int c = bx & 15, dtile = (bx >> 4) & 31, b = bx >> 9;
  int d = dtile * 16 + dsub;
  float Adn = -__expf(A_log[((size_t)(dir * NLc + layer) * DIc + d) * Nn + n]);
  int l0 = dir ? (Ls - 1) : 0;
  int step = dir ? -1 : 1;
  size_t base = (size_t)b * Ls;
  float a = 1.f, s = 0.f;
#pragma unroll 4
  for (int j = 0; j < CHUNK; j++) {
    int l = l0 + (c * CHUNK + j) * step;
    size_t idx = base + l;
    float dv = dlt[idx * DIc + d];
    float uv = u[idx * DIc + d];
    float bm = xd[idx * 48 + 16 + n];
    float dA = __expf(dv * Adn);
    a *= dA;
    s = dA * s + dv * bm * uv;
  }
  int ch = ((dir * Bb + b) * DIc + d) * Nn + n;
  P[(size_t)c * NCHAIN + ch] = make_float2(a, s);
}

__global__ __launch_bounds__(256) void scan_mid(float2* __restrict__ P) {
  int ch = blockIdx.x * 256 + threadIdx.x;
  float s = 0.f;
#pragma unroll
  for (int c = 0; c < NCH; c++) {
    float2 ac = P[(size_t)c * NCHAIN + ch];
    P[(size_t)c * NCHAIN + ch].x = s;
    s = ac.x * s + ac.y;
  }
}

__global__ __launch_bounds__(256) void scan_p2(
    const float* __restrict__ delta, const float* __restrict__ xc,
    const float* __restrict__ xdbl, const float* __restrict__ xr,
    const float* __restrict__ A_log, const float* __restrict__ Dp,
    const float2* __restrict__ P, __hip_bfloat16* __restrict__ ygb, int layer) {
  int dir = blockIdx.z;
  const float* dlt = delta + (size_t)dir * SZ_XC;
  const float* u   = xc + (size_t)dir * SZ_XC;
  const float* xd  = xdbl + (size_t)dir * SZ_XD;
  const float* res = xr + (size_t)dir * SZ_XR;
  __hip_bfloat16* out = ygb + (size_t)dir * SZ_XC;
  int t = threadIdx.x;
  int n = t & 15, dsub = t >> 4;
  int bx = blockIdx.x;
  int c = bx & 15, dtile = (bx >> 4) & 31, b = bx >> 9;
  int d = dtile * 16 + dsub;
  float Adn = -__expf(A_log[((size_t)(dir * NLc + layer) * DIc + d) * Nn + n]);
  float Dd = Dp[(size_t)(dir * NLc + layer) * DIc + d];
  int l0 = dir ? (Ls - 1) : 0;
  int step = dir ? -1 : 1;
  size_t base = (size_t)b * Ls;
  int ch = ((dir * Bb + b) * DIc + d) * Nn + n;
  float s = P[(size_t)c * NCHAIN + ch].x;
#pragma unroll 4
  for (int j = 0; j < CHUNK; j++) {
    int l = l0 + (c * CHUNK + j) * step;
    size_t idx = base + l;
    float dv = dlt[idx * DIc + d];
    float uv = u[idx * DIc + d];
    float bm = xd[idx * 48 + 16 + n];
    float cm = xd[idx * 48 + 32 + n];
    float dA = __expf(dv * Adn);
    s = dA * s + dv * bm * uv;
    float v = s * cm;
    v += __shfl_xor(v, 1); v += __shfl_xor(v, 2);
    v += __shfl_xor(v, 4); v += __shfl_xor(v, 8);
    if (n == 0) {
      float rv = res[idx * 1024 + DIc + d];
      float sig = 1.f / (1.f + __expf(-rv));
      out[idx * DIc + d] = __float2bfloat16((v + uv * Dd) * (rv * sig));
    }
  }
}

// ---------------- combine: x = 3x + o0 + o1 ----------------
__global__ __launch_bounds__(256) void combine_k(float* __restrict__ x,
                                                 const float* __restrict__ o) {
  size_t g = (size_t)blockIdx.x * 256 + threadIdx.x;
  x[g] = 3.f * x[g] + o[g] + o[g + SZ_X];
}

__global__ __launch_bounds__(256) void copy_k(const float* __restrict__ a,
                                              float* __restrict__ b) {
  size_t g = (size_t)blockIdx.x * 256 + threadIdx.x;
  b[g] = a[g];
}

// ---------------- MLP norm over L (transposed read) -> bf16 ----------------
__global__ __launch_bounds__(256) void mlp_norm_k(
    const float* __restrict__ x, const float* __restrict__ w,
    const float* __restrict__ bb, __hip_bfloat16* __restrict__ hnb, int use_ln) {
  int r = blockIdx.x;           // b*DM + m
  int b = r >> 8, m = r & 255;
  int t = threadIdx.x;
  const float* xb = x + (size_t)b * Ls * DMc + m;
  float v0 = xb[(size_t)t * DMc];
  float v1 = xb[(size_t)(t + 256) * DMc];
  float a = v0 + v1, q = v0 * v0 + v1 * v1;
  __shared__ float sa[4], sb[4];
  block_reduce_2(a, q, sa, sb);
  float mu = use_ln ? a * (1.f / Ls) : 0.f;
  float var = q * (1.f / Ls) - mu * mu;
  float inv = rsqrtf(var + 1e-5f);
  __hip_bfloat16* o = hnb + (size_t)r * Ls;
  o[t] = __float2bfloat16((v0 - mu) * inv * w[t] + (use_ln ? bb[t] : 0.f));
  o[t + 256] = __float2bfloat16((v1 - mu) * inv * w[t + 256] + (use_ln ? bb[t + 256] : 0.f));
}

// ---------------- add-back: x[b,l,m] += h2[(b*DM+m)*L + l] ----------------
__global__ __launch_bounds__(256) void addback_k(float* __restrict__ x,
                                                 const float* __restrict__ h2) {
  size_t g = (size_t)blockIdx.x * 256 + threadIdx.x;
  int m = (int)(g & 255);
  int r = (int)(g >> 8);
  int l = r & 511, b = r >> 9;
  x[g] += h2[((size_t)(b * DMc + m)) * Ls + l];
}

// =======================================================================
extern "C" void kernel_launch(void* const* d_in, const int* in_sizes, int n_in,
                              void* d_out, int out_size, void* d_ws, size_t ws_size,
                              hipStream_t stream) {
  const float* input_ids = (const float*)d_in[0];
  const float* emb_W     = (const float*)d_in[1];
  const float* emb_b     = (const float*)d_in[2];
  const float* ln_g      = (const float*)d_in[3];
  const float* ln_b      = (const float*)d_in[4];
  const float* inproj_W  = (const float*)d_in[5];
  const float* inproj_b  = (const float*)d_in[6];
  const float* conv_w    = (const float*)d_in[7];
  const float* conv_b    = (const float*)d_in[8];
  const float* xproj_W   = (const float*)d_in[9];
  const float* dtproj_W  = (const float*)d_in[10];
  const float* dtproj_b  = (const float*)d_in[11];
  const float* outproj_W = (const float*)d_in[12];
  const float* outproj_b = (const float*)d_in[13];
  const float* A_log     = (const float*)d_in[14];
  const float* Dp        = (const float*)d_in[15];
  const float* lin_norm_w= (const float*)d_in[16];
  const float* lin_norm_b= (const float*)d_in[17];
  const float* lin_W1    = (const float*)d_in[18];
  const float* lin_b1    = (const float*)d_in[19];
  const float* lin_W2    = (const float*)d_in[20];
  const float* lin_b2    = (const float*)d_in[21];
  const float* normf_g   = (const float*)d_in[22];
  const float* normf_b   = (const float*)d_in[23];
  float* out = (float*)d_out;

  float* ws    = (float*)d_ws;
  float* x     = ws + X_OFF;
  float* resid = ws + RES_OFF;
  float* o     = ws + O_OFF;
  float* xr    = ws + XR_OFF;
  float* xc    = ws + XC_OFF;
  float* xdbl  = ws + XDBL_OFF;
  float* delta = ws + DELTA_OFF;
  float* h1f   = ws + H1F_OFF;
  float* h2    = ws + H2_OFF;
  float2* P    = (float2*)(ws + P_OFF);

  __hip_bfloat16* xlnb  = (__hip_bfloat16*)(ws + XLNB_OFF);
  __hip_bfloat16* xdblb = (__hip_bfloat16*)(ws + XDBLB_OFF);
  __hip_bfloat16* xcb   = (__hip_bfloat16*)(ws + XCB_OFF);
  __hip_bfloat16* ygb   = (__hip_bfloat16*)(ws + YGB_OFF);
  __hip_bfloat16* hnb   = (__hip_bfloat16*)(ws + HNB_OFF);
  __hip_bfloat16* h1b   = (__hip_bfloat16*)(ws + H1B_OFF);
  __hip_bfloat16* idsb  = (__hip_bfloat16*)(ws + IDSB_OFF);
  __hip_bfloat16* wemb  = (__hip_bfloat16*)(ws + WEMB_OFF);
  __hip_bfloat16* wbin  = (__hip_bfloat16*)(ws + WBIN_OFF);
  __hip_bfloat16* wbx   = (__hip_bfloat16*)(ws + WBX_OFF);
  __hip_bfloat16* wbdt  = (__hip_bfloat16*)(ws + WBDT_OFF);
  __hip_bfloat16* wbout = (__hip_bfloat16*)(ws + WBOUT_OFF);
  __hip_bfloat16* wb1   = (__hip_bfloat16*)(ws + WB1_OFF);
  __hip_bfloat16* wb2   = (__hip_bfloat16*)(ws + WB2_OFF);

  // 0. cast weights + input to bf16 (one launch, 8 segments)
  CastArgs ca;
  ca.seg[0] = { input_ids, idsb,  (int)(ROWS * Vv / 4) };
  ca.seg[1] = { emb_W,     wemb,  (int)(DMc * Vv / 4) };
  ca.seg[2] = { inproj_W,  wbin,  (int)(2 * NLc * 2 * DIc * DMc / 4) };
  ca.seg[3] = { xproj_W,   wbx,   (int)(2 * NLc * 48 * DIc / 4) };
  ca.seg[4] = { dtproj_W,  wbdt,  (int)(2 * NLc * DIc * DTRc / 4) };
  ca.seg[5] = { outproj_W, wbout, (int)(2 * NLc * DMc * DIc / 4) };
  ca.seg[6] = { lin_W1,    wb1,   (int)(NLc * HIDc * Ls / 4) };
  ca.seg[7] = { lin_W2,    wb2,   (int)(NLc * Ls * HIDc / 4) };
  cast8_k<<<dim3(128, 8, 1), 256, 0, stream>>>(ca);

  // 1. embedding: x = ids @ emb_W^T + emb_b   (2048x256x256)
  gemm_bf<0, false><<<dim3(4, 32, 1), 256, 0, stream>>>(
      idsb, Vv, 0, wemb, Vv, 0, emb_b, 0, x, nullptr, DMc, 0, ROWS, DMc, Vv);
  copy_k<<<(int)(SZ_X / 256), 256, 0, stream>>>(x, resid);

  for (int i = 0; i < NLc; i++) {
    ln_dm_k<<<dim3(ROWS, 1, 2), 256, 0, stream>>>(x, ln_g, ln_b, xlnb, i);
    // inproj: 2048 x 1024 x 256
    gemm_bf<0, false><<<dim3(16, 32, 2), 256, 0, stream>>>(
        xlnb, DMc, (long)SZ_X,
        wbin + (size_t)i * 2 * DIc * DMc, DMc, (long)NLc * 2 * DIc * DMc,
        inproj_b + (size_t)i * 2 * DIc, (long)NLc * 2 * DIc,
        xr, nullptr, 2 * DIc, (long)SZ_XR, ROWS, 2 * DIc, DMc);
    conv_silu_k<<<dim3(ROWS * DIc / 256, 1, 2), 256, 0, stream>>>(
        xr, conv_w, conv_b, xc, xcb, i);
    // xproj: 2048 x 48 x 512 (f32 + bf16 outs)
    gemm_bf<0, true><<<dim3(1, 32, 2), 256, 0, stream>>>(
        xcb, DIc, (long)SZ_XC,
        wbx + (size_t)i * 48 * DIc, DIc, (long)NLc * 48 * DIc,
        nullptr, 0, xdbl, xdblb, 48, (long)SZ_XD, ROWS, 48, DIc);
    // dtproj + softplus: 2048 x 512 x 16
    gemm_bf<2, false><<<dim3(8, 32, 2), 256, 0, stream>>>(
        xdblb, 48, (long)SZ_XD,
        wbdt + (size_t)i * DIc * DTRc, DTRc, (long)NLc * DIc * DTRc,
        dtproj_b + (size_t)i * DIc, (long)NLc * DIc,
        delta, nullptr, DIc, (long)SZ_XC, ROWS, DIc, DTRc);
    // chunked selective scan + gate
    scan_p1<<<dim3(Bb * 32 * NCH, 1, 2), 256, 0, stream>>>(
        delta, xc, xdbl, A_log, P, i);
    scan_mid<<<dim3(NCHAIN / 256, 1, 1), 256, 0, stream>>>(P);
    scan_p2<<<dim3(Bb * 32 * NCH, 1, 2), 256, 0, stream>>>(
        delta, xc, xdbl, xr, A_log, Dp, P, ygb, i);
    // outproj: 2048 x 256 x 512
    gemm_bf<0, false><<<dim3(4, 32, 2), 256, 0, stream>>>(
        ygb, DIc, (long)SZ_XC,
        wbout + (size_t)i * DMc * DIc, DIc, (long)NLc * DMc * DIc,
        outproj_b + (size_t)i * DMc, (long)NLc * DMc,
        o, nullptr, DMc, (long)SZ_X, ROWS, DMc, DIc);
    combine_k<<<(int)(SZ_X / 256), 256, 0, stream>>>(x, o);
    // MLP over L axis
    mlp_norm_k<<<Bb * DMc, 256, 0, stream>>>(
        x, lin_norm_w + (size_t)i * Ls, lin_norm_b + (size_t)i * Ls, hnb, i == 0 ? 1 : 0);
    gemm_bf<1, true><<<dim3(8, 16, 1), 256, 0, stream>>>(
        hnb, Ls, 0, wb1 + (size_t)i * HIDc * Ls, Ls, 0,
        lin_b1 + (size_t)i * HIDc, 0, h1f, h1b, HIDc, 0, Bb * DMc, HIDc, Ls);
    gemm_bf<0, false><<<dim3(8, 16, 1), 256, 0, stream>>>(
        h1b, HIDc, 0, wb2 + (size_t)i * Ls * HIDc, HIDc, 0,
        lin_b2 + (size_t)i * Ls, 0, h2, nullptr, Ls, 0, Bb * DMc, Ls, HIDc);
    addback_k<<<(int)(SZ_X / 256), 256, 0, stream>>>(x, h2);
  }
  ln_final_k<<<ROWS, 256, 0, stream>>>(x, resid, normf_g, normf_b, out);
}

// Round 4
// 507.158 us; speedup vs baseline: 4.5981x; 1.3339x over previous
//
#include <hip/hip_runtime.h>
#include <hip/hip_bf16.h>
#include <cstddef>

// ---- problem constants ----
constexpr int Bb = 4, Ls = 512, Vv = 256, DMc = 256, DIc = 512, Nn = 16;
constexpr int DTRc = 16, NLc = 4, HIDc = 512;
constexpr int ROWS = Bb * Ls;  // 2048

// chunked-scan constants: thread = (dir,b,d,chunk) with 16 n-states in regs
constexpr int CHUNK = 16, NCH = Ls / CHUNK;          // 32 chunks
constexpr int NCHAIN = 2 * Bb * DIc * Nn;            // 65536 chains (incl dir)

// per-direction buffer sizes (floats)
constexpr size_t SZ_X  = (size_t)ROWS * DMc;      // 524288
constexpr size_t SZ_XR = (size_t)ROWS * 2 * DIc;  // 2097152
constexpr size_t SZ_XC = (size_t)ROWS * DIc;      // 1048576
constexpr size_t SZ_XD = (size_t)ROWS * 48;       // 98304

// workspace layout (float offsets)
constexpr size_t X_OFF    = 0;
constexpr size_t RES_OFF  = SZ_X;
constexpr size_t O_OFF    = 2 * SZ_X;              // 2 dirs (o f32)
constexpr size_t XLN_OFF  = 4 * SZ_X;              // (f32 region reused for bf16)
constexpr size_t XR_OFF   = 6 * SZ_X;              // 2 dirs x SZ_XR
constexpr size_t XC_OFF   = XR_OFF + 2 * SZ_XR;    // 2 dirs
constexpr size_t XDBL_OFF = XC_OFF + 2 * SZ_XC;    // 2 dirs (f32)
constexpr size_t DELTA_OFF= XDBL_OFF + 2 * SZ_XD;  // 2 dirs
constexpr size_t YG_OFF   = DELTA_OFF + 2 * SZ_XC; // region reused for bf16 bufs
constexpr size_t WS_END0  = YG_OFF + 2 * SZ_XC;    // 13,828,096 floats

// scan transfer scratch P: NCH*NCHAIN ushort2 = 8 MB, aliases [O_OFF, O_OFF+4*SZ_X)
// (o f32 + xlnb + xdblb — all dead during the scan phase)
constexpr size_t P_OFF = O_OFF;

// bf16 activation buffers aliased into dead f32 regions (offsets in floats)
constexpr size_t XLNB_OFF  = XLN_OFF;                 // 2*SZ_X bf16 (524288 fl)
constexpr size_t XDBLB_OFF = XLN_OFF + 524288;        // 2*SZ_XD bf16 (98304 fl)
constexpr size_t XCB_OFF   = YG_OFF;                  // 2*SZ_XC bf16 (1048576 fl)
constexpr size_t YGB_OFF   = YG_OFF + 1048576;        // 2*SZ_XC bf16 (1048576 fl)
// MLP-phase aliases inside XR region (xr f32 dead after scan)
constexpr size_t HNB_OFF = XR_OFF;                    // SZ_X bf16 (262144 fl)
constexpr size_t H1F_OFF = XR_OFF + 262144;           // SZ_X f32
constexpr size_t H1B_OFF = XR_OFF + 786432;           // SZ_X bf16 (262144 fl)
constexpr size_t H2_OFF  = XR_OFF + 1048576;          // SZ_X f32
// embedding-phase aliases inside XR region (pre-layer only)
constexpr size_t IDSB_OFF = XR_OFF;                   // ROWS*Vv bf16 (262144 fl)
constexpr size_t WEMB_OFF = XR_OFF + 262144;          // DMc*Vv bf16 (32768 fl)
// persistent bf16 weights (new region)
constexpr size_t WBIN_OFF  = WS_END0;                 // 2*4*1024*256 bf16
constexpr size_t WBX_OFF   = WBIN_OFF + 1048576;      // 2*4*48*512 bf16
constexpr size_t WBDT_OFF  = WBX_OFF + 98304;         // 2*4*512*16 bf16
constexpr size_t WBOUT_OFF = WBDT_OFF + 32768;        // 2*4*256*512 bf16
constexpr size_t WB1_OFF   = WBOUT_OFF + 524288;      // 4*512*512 bf16
constexpr size_t WB2_OFF   = WB1_OFF + 524288;        // 4*512*512 bf16

typedef __attribute__((ext_vector_type(8))) short bfrag8;
typedef __attribute__((ext_vector_type(4))) float f32x4;

__device__ __forceinline__ unsigned short f2b(float v) {
  __hip_bfloat16 h = __float2bfloat16(v);
  return *reinterpret_cast<unsigned short*>(&h);
}
__device__ __forceinline__ float b2f(unsigned short u) {
  unsigned int x = ((unsigned int)u) << 16;
  return *reinterpret_cast<float*>(&x);
}

// ---------------- fused f32->bf16 cast, 8 segments, one launch ----------------
struct CastSeg { const float* s; __hip_bfloat16* d; int n4; };
struct CastArgs { CastSeg seg[8]; };
__global__ __launch_bounds__(256) void cast8_k(CastArgs a) {
  CastSeg sg = a.seg[blockIdx.y];
  for (int i = blockIdx.x * 256 + threadIdx.x; i < sg.n4; i += gridDim.x * 256) {
    float4 v = reinterpret_cast<const float4*>(sg.s)[i];
    ushort4 u;
    u.x = f2b(v.x); u.y = f2b(v.y); u.z = f2b(v.z); u.w = f2b(v.w);
    *reinterpret_cast<ushort4*>(sg.d + (size_t)i * 4) = u;
  }
}

// ---------------- bf16 MFMA GEMM: C = A @ W^T + bias, act ----------------
template <int ACT, bool BF16OUT>
__global__ __launch_bounds__(256) void gemm_bf(
    const __hip_bfloat16* __restrict__ A, int lda, long sA,
    const __hip_bfloat16* __restrict__ W, int ldw, long sW,
    const float* __restrict__ bias, long sB,
    float* __restrict__ C, __hip_bfloat16* __restrict__ Cb, int ldc, long sC,
    int M, int N, int K) {
  int z = blockIdx.z;
  A += (size_t)z * sA;
  W += (size_t)z * sW;
  if (bias) bias += (size_t)z * sB;
  C += (size_t)z * sC;
  if (BF16OUT) Cb += (size_t)z * sC;

  constexpr int LDT = 40;
  __shared__ unsigned short As[64 * LDT];
  __shared__ unsigned short Wt[64 * LDT];
  int tid = threadIdx.x;
  int l = tid & 63, w = tid >> 6;
  int wr = w >> 1, wc = w & 1;
  int m0 = blockIdx.y * 64, n0 = blockIdx.x * 64;
  int lrow = l & 15, lk = (l >> 4) * 8;

  f32x4 zero = {0.f, 0.f, 0.f, 0.f};
  f32x4 acc[2][2];
  acc[0][0] = zero; acc[0][1] = zero; acc[1][0] = zero; acc[1][1] = zero;

  int sr = tid >> 2, sk = (tid & 3) * 8;

  for (int k0 = 0; k0 < K; k0 += 32) {
    uint4 va = make_uint4(0, 0, 0, 0), vw = make_uint4(0, 0, 0, 0);
    if (k0 + sk < K) {
      va = *reinterpret_cast<const uint4*>(A + (size_t)(m0 + sr) * lda + k0 + sk);
      int rn = n0 + sr; if (rn >= N) rn = N - 1;
      vw = *reinterpret_cast<const uint4*>(W + (size_t)rn * ldw + k0 + sk);
    }
    *reinterpret_cast<uint4*>(&As[sr * LDT + sk]) = va;
    *reinterpret_cast<uint4*>(&Wt[sr * LDT + sk]) = vw;
    __syncthreads();
    bfrag8 af[2], bf[2];
#pragma unroll
    for (int f = 0; f < 2; f++) {
      af[f] = *reinterpret_cast<const bfrag8*>(&As[(wr * 32 + f * 16 + lrow) * LDT + lk]);
      bf[f] = *reinterpret_cast<const bfrag8*>(&Wt[(wc * 32 + f * 16 + lrow) * LDT + lk]);
    }
#pragma unroll
    for (int fr = 0; fr < 2; fr++)
#pragma unroll
      for (int fc = 0; fc < 2; fc++)
        acc[fr][fc] = __builtin_amdgcn_mfma_f32_16x16x32_bf16(af[fr], bf[fc], acc[fr][fc], 0, 0, 0);
    __syncthreads();
  }

#pragma unroll
  for (int fr = 0; fr < 2; fr++) {
    int row = m0 + wr * 32 + fr * 16 + (l >> 4) * 4;
#pragma unroll
    for (int fc = 0; fc < 2; fc++) {
      int col = n0 + wc * 32 + fc * 16 + (l & 15);
      if (col < N) {
        float bv = bias ? bias[col] : 0.f;
#pragma unroll
        for (int j = 0; j < 4; j++) {
          float v = acc[fr][fc][j] + bv;
          if (ACT == 1) v = fmaxf(v, 0.f);
          if (ACT == 2) v = fmaxf(v, 0.f) + log1pf(__expf(-fabsf(v)));
          C[(size_t)(row + j) * ldc + col] = v;
          if (BF16OUT) Cb[(size_t)(row + j) * ldc + col] = __float2bfloat16(v);
        }
      }
    }
  }
}

// ---------------- block reduce (256 threads, 2 values) ----------------
__device__ __forceinline__ void block_reduce_2(float& a, float& b, float* sa, float* sb) {
#pragma unroll
  for (int m = 32; m >= 1; m >>= 1) {
    a += __shfl_xor(a, m);
    b += __shfl_xor(b, m);
  }
  int wid = threadIdx.x >> 6, lane = threadIdx.x & 63;
  if (lane == 0) { sa[wid] = a; sb[wid] = b; }
  __syncthreads();
  a = sa[0] + sa[1] + sa[2] + sa[3];
  b = sb[0] + sb[1] + sb[2] + sb[3];
}

// ---------------- LN over DM (z = dir) -> bf16 ----------------
__global__ __launch_bounds__(256) void ln_dm_k(
    const float* __restrict__ x, const float* __restrict__ g,
    const float* __restrict__ bt, __hip_bfloat16* __restrict__ xlnb, int layer) {
  int dir = blockIdx.z;
  g += (size_t)(dir * NLc + layer) * DMc;
  bt += (size_t)(dir * NLc + layer) * DMc;
  __hip_bfloat16* out = xlnb + (size_t)dir * SZ_X;
  int row = blockIdx.x, t = threadIdx.x;
  float v = x[(size_t)row * DMc + t];
  float a = v, q = v * v;
  __shared__ float sa[4], sb[4];
  block_reduce_2(a, q, sa, sb);
  float mu = a * (1.f / DMc);
  float var = q * (1.f / DMc) - mu * mu;
  float inv = rsqrtf(var + 1e-5f);
  out[(size_t)row * DMc + t] = __float2bfloat16((v - mu) * inv * g[t] + bt[t]);
}

// ---------------- final LN(x + resid) ----------------
__global__ __launch_bounds__(256) void ln_final_k(
    const float* __restrict__ x, const float* __restrict__ resid,
    const float* __restrict__ g, const float* __restrict__ bt,
    float* __restrict__ out) {
  int row = blockIdx.x, t = threadIdx.x;
  float v = x[(size_t)row * DMc + t] + resid[(size_t)row * DMc + t];
  float a = v, q = v * v;
  __shared__ float sa[4], sb[4];
  block_reduce_2(a, q, sa, sb);
  float mu = a * (1.f / DMc);
  float var = q * (1.f / DMc) - mu * mu;
  float inv = rsqrtf(var + 1e-5f);
  out[(size_t)row * DMc + t] = (v - mu) * inv * g[t] + bt[t];
}

// ---------------- causal depthwise conv (DC=4) + SiLU (z = dir) ----------------
__global__ __launch_bounds__(256) void conv_silu_k(
    const float* __restrict__ xr, const float* __restrict__ cw,
    const float* __restrict__ cb, float* __restrict__ xc,
    __hip_bfloat16* __restrict__ xcb, int layer) {
  int dir = blockIdx.z;
  const float* xin = xr + (size_t)dir * SZ_XR;
  const float* w = cw + (size_t)(dir * NLc + layer) * DIc * 4;
  const float* bb = cb + (size_t)(dir * NLc + layer) * DIc;
  float* out = xc + (size_t)dir * SZ_XC;
  __hip_bfloat16* outb = xcb + (size_t)dir * SZ_XC;
  int gid = blockIdx.x * 256 + threadIdx.x;
  int d = gid & 511, row = gid >> 9, l = row & 511;
  float w0 = w[d * 4 + 0], w1 = w[d * 4 + 1], w2 = w[d * 4 + 2], w3 = w[d * 4 + 3];
  float acc = bb[d];
  if (dir == 0) {
    acc += w3 * xin[(size_t)row * 1024 + d];
    if (l >= 1) acc += w2 * xin[(size_t)(row - 1) * 1024 + d];
    if (l >= 2) acc += w1 * xin[(size_t)(row - 2) * 1024 + d];
    if (l >= 3) acc += w0 * xin[(size_t)(row - 3) * 1024 + d];
  } else {
    acc += w3 * xin[(size_t)row * 1024 + d];
    if (l + 1 < Ls) acc += w2 * xin[(size_t)(row + 1) * 1024 + d];
    if (l + 2 < Ls) acc += w1 * xin[(size_t)(row + 2) * 1024 + d];
    if (l + 3 < Ls) acc += w0 * xin[(size_t)(row + 3) * 1024 + d];
  }
  float r = acc * (1.f / (1.f + __expf(-acc)));
  out[(size_t)row * DIc + d] = r;
  outb[(size_t)row * DIc + d] = __float2bfloat16(r);
}

// ---------------- chunked selective scan, 16 n-states per thread ----------------
// thread = (dir, b, d, chunk). Wave lanes = 64 consecutive d (coalesced dv/uv/rv;
// bm/cm broadcast — same (b,l) for the whole block). No shfl, no divergence.
// pass 1: compute chunk transfer a_n = exp(Adn*sum dv), c_n = local end state.
__global__ __launch_bounds__(256) void scan_p1(
    const float* __restrict__ delta, const float* __restrict__ xc,
    const float* __restrict__ xdbl, const float* __restrict__ A_log,
    ushort2* __restrict__ P, int layer) {
  int dir = blockIdx.z;
  const float* dlt = delta + (size_t)dir * SZ_XC;
  const float* u   = xc + (size_t)dir * SZ_XC;
  const float* xd  = xdbl + (size_t)dir * SZ_XD;
  int bx = blockIdx.x;                 // 256 blocks: half(1) x chunk(32) x b(4)
  int half = bx & 1, c = (bx >> 1) & 31, b = bx >> 6;
  int d = half * 256 + threadIdx.x;
  float Adn[16];
  const float* alog = A_log + ((size_t)(dir * NLc + layer) * DIc + d) * Nn;
#pragma unroll
  for (int n = 0; n < 16; n++) Adn[n] = -__expf(alog[n]);
  int l0 = dir ? (Ls - 1) : 0, step = dir ? -1 : 1;
  size_t base = (size_t)b * Ls;
  float cst[16];
#pragma unroll
  for (int n = 0; n < 16; n++) cst[n] = 0.f;
  float S = 0.f;
#pragma unroll
  for (int j = 0; j < CHUNK; j++) {
    int l = l0 + (c * CHUNK + j) * step;
    size_t idx = base + l;
    float dv = dlt[idx * DIc + d];
    float uv = u[idx * DIc + d];
    float bmv[16];
    *reinterpret_cast<float4*>(&bmv[0])  = *reinterpret_cast<const float4*>(xd + idx * 48 + 16);
    *reinterpret_cast<float4*>(&bmv[4])  = *reinterpret_cast<const float4*>(xd + idx * 48 + 20);
    *reinterpret_cast<float4*>(&bmv[8])  = *reinterpret_cast<const float4*>(xd + idx * 48 + 24);
    *reinterpret_cast<float4*>(&bmv[12]) = *reinterpret_cast<const float4*>(xd + idx * 48 + 28);
    float dvu = dv * uv;
    S += dv;
#pragma unroll
    for (int n = 0; n < 16; n++) {
      float dA = __expf(dv * Adn[n]);
      cst[n] = fmaf(dA, cst[n], dvu * bmv[n]);
    }
  }
  size_t cb = ((size_t)(dir * Bb + b) * DIc + d) * Nn;
  ushort2* pp = P + (size_t)c * NCHAIN + cb;
#pragma unroll
  for (int n = 0; n < 16; n++)
    pp[n] = make_ushort2(f2b(__expf(S * Adn[n])), f2b(cst[n]));
}

// pass 2: combine the 32 chunk transfers per chain; overwrite .x with the
// state ENTERING each chunk (f32 accumulation, bf16 storage).
__global__ __launch_bounds__(256) void scan_mid(ushort2* __restrict__ P) {
  int ch = blockIdx.x * 256 + threadIdx.x;
  float s = 0.f;
#pragma unroll
  for (int c = 0; c < NCH; c++) {
    ushort2 ac = P[(size_t)c * NCHAIN + ch];
    P[(size_t)c * NCHAIN + ch].x = f2b(s);
    s = fmaf(b2f(ac.x), s, b2f(ac.y));
  }
}

// pass 3: re-scan each chunk from its init state; reduce over n in registers,
// gate with silu(res), write bf16 yg.
__global__ __launch_bounds__(256) void scan_p2(
    const float* __restrict__ delta, const float* __restrict__ xc,
    const float* __restrict__ xdbl, const float* __restrict__ xr,
    const float* __restrict__ A_log, const float* __restrict__ Dp,
    const ushort2* __restrict__ P, __hip_bfloat16* __restrict__ ygb, int layer) {
  int dir = blockIdx.z;
  const float* dlt = delta + (size_t)dir * SZ_XC;
  const float* u   = xc + (size_t)dir * SZ_XC;
  const float* xd  = xdbl + (size_t)dir * SZ_XD;
  const float* res = xr + (size_t)dir * SZ_XR;
  __hip_bfloat16* out = ygb + (size_t)dir * SZ_XC;
  int bx = blockIdx.x;
  int half = bx & 1, c = (bx >> 1) & 31, b = bx >> 6;
  int d = half * 256 + threadIdx.x;
  float Adn[16];
  const float* alog = A_log + ((size_t)(dir * NLc + layer) * DIc + d) * Nn;
#pragma unroll
  for (int n = 0; n < 16; n++) Adn[n] = -__expf(alog[n]);
  float Dd = Dp[(size_t)(dir * NLc + layer) * DIc + d];
  int l0 = dir ? (Ls - 1) : 0, step = dir ? -1 : 1;
  size_t base = (size_t)b * Ls;
  size_t cb = ((size_t)(dir * Bb + b) * DIc + d) * Nn;
  const ushort2* pp = P + (size_t)c * NCHAIN + cb;
  float s[16];
#pragma unroll
  for (int n = 0; n < 16; n++) s[n] = b2f(pp[n].x);
#pragma unroll
  for (int j = 0; j < CHUNK; j++) {
    int l = l0 + (c * CHUNK + j) * step;
    size_t idx = base + l;
    float dv = dlt[idx * DIc + d];
    float uv = u[idx * DIc + d];
    float bmv[16], cmv[16];
    *reinterpret_cast<float4*>(&bmv[0])  = *reinterpret_cast<const float4*>(xd + idx * 48 + 16);
    *reinterpret_cast<float4*>(&bmv[4])  = *reinterpret_cast<const float4*>(xd + idx * 48 + 20);
    *reinterpret_cast<float4*>(&bmv[8])  = *reinterpret_cast<const float4*>(xd + idx * 48 + 24);
    *reinterpret_cast<float4*>(&bmv[12]) = *reinterpret_cast<const float4*>(xd + idx * 48 + 28);
    *reinterpret_cast<float4*>(&cmv[0])  = *reinterpret_cast<const float4*>(xd + idx * 48 + 32);
    *reinterpret_cast<float4*>(&cmv[4])  = *reinterpret_cast<const float4*>(xd + idx * 48 + 36);
    *reinterpret_cast<float4*>(&cmv[8])  = *reinterpret_cast<const float4*>(xd + idx * 48 + 40);
    *reinterpret_cast<float4*>(&cmv[12]) = *reinterpret_cast<const float4*>(xd + idx * 48 + 44);
    float dvu = dv * uv;
    float y = 0.f;
#pragma unroll
    for (int n = 0; n < 16; n++) {
      float dA = __expf(dv * Adn[n]);
      s[n] = fmaf(dA, s[n], dvu * bmv[n]);
      y = fmaf(s[n], cmv[n], y);
    }
    float rv = res[idx * 1024 + DIc + d];
    float sig = 1.f / (1.f + __expf(-rv));
    out[idx * DIc + d] = __float2bfloat16((y + uv * Dd) * (rv * sig));
  }
}

// ---------------- combine: x = 3x + o0 + o1 ----------------
__global__ __launch_bounds__(256) void combine_k(float* __restrict__ x,
                                                 const float* __restrict__ o) {
  size_t g = (size_t)blockIdx.x * 256 + threadIdx.x;
  x[g] = 3.f * x[g] + o[g] + o[g + SZ_X];
}

__global__ __launch_bounds__(256) void copy_k(const float* __restrict__ a,
                                              float* __restrict__ b) {
  size_t g = (size_t)blockIdx.x * 256 + threadIdx.x;
  b[g] = a[g];
}

// ---------------- MLP norm over L (transposed read) -> bf16 ----------------
__global__ __launch_bounds__(256) void mlp_norm_k(
    const float* __restrict__ x, const float* __restrict__ w,
    const float* __restrict__ bb, __hip_bfloat16* __restrict__ hnb, int use_ln) {
  int r = blockIdx.x;           // b*DM + m
  int b = r >> 8, m = r & 255;
  int t = threadIdx.x;
  const float* xb = x + (size_t)b * Ls * DMc + m;
  float v0 = xb[(size_t)t * DMc];
  float v1 = xb[(size_t)(t + 256) * DMc];
  float a = v0 + v1, q = v0 * v0 + v1 * v1;
  __shared__ float sa[4], sb[4];
  block_reduce_2(a, q, sa, sb);
  float mu = use_ln ? a * (1.f / Ls) : 0.f;
  float var = q * (1.f / Ls) - mu * mu;
  float inv = rsqrtf(var + 1e-5f);
  __hip_bfloat16* o = hnb + (size_t)r * Ls;
  o[t] = __float2bfloat16((v0 - mu) * inv * w[t] + (use_ln ? bb[t] : 0.f));
  o[t + 256] = __float2bfloat16((v1 - mu) * inv * w[t + 256] + (use_ln ? bb[t + 256] : 0.f));
}

// ---------------- add-back: x[b,l,m] += h2[(b*DM+m)*L + l] ----------------
__global__ __launch_bounds__(256) void addback_k(float* __restrict__ x,
                                                 const float* __restrict__ h2) {
  size_t g = (size_t)blockIdx.x * 256 + threadIdx.x;
  int m = (int)(g & 255);
  int r = (int)(g >> 8);
  int l = r & 511, b = r >> 9;
  x[g] += h2[((size_t)(b * DMc + m)) * Ls + l];
}

// =======================================================================
extern "C" void kernel_launch(void* const* d_in, const int* in_sizes, int n_in,
                              void* d_out, int out_size, void* d_ws, size_t ws_size,
                              hipStream_t stream) {
  const float* input_ids = (const float*)d_in[0];
  const float* emb_W     = (const float*)d_in[1];
  const float* emb_b     = (const float*)d_in[2];
  const float* ln_g      = (const float*)d_in[3];
  const float* ln_b      = (const float*)d_in[4];
  const float* inproj_W  = (const float*)d_in[5];
  const float* inproj_b  = (const float*)d_in[6];
  const float* conv_w    = (const float*)d_in[7];
  const float* conv_b    = (const float*)d_in[8];
  const float* xproj_W   = (const float*)d_in[9];
  const float* dtproj_W  = (const float*)d_in[10];
  const float* dtproj_b  = (const float*)d_in[11];
  const float* outproj_W = (const float*)d_in[12];
  const float* outproj_b = (const float*)d_in[13];
  const float* A_log     = (const float*)d_in[14];
  const float* Dp        = (const float*)d_in[15];
  const float* lin_norm_w= (const float*)d_in[16];
  const float* lin_norm_b= (const float*)d_in[17];
  const float* lin_W1    = (const float*)d_in[18];
  const float* lin_b1    = (const float*)d_in[19];
  const float* lin_W2    = (const float*)d_in[20];
  const float* lin_b2    = (const float*)d_in[21];
  const float* normf_g   = (const float*)d_in[22];
  const float* normf_b   = (const float*)d_in[23];
  float* out = (float*)d_out;

  float* ws    = (float*)d_ws;
  float* x     = ws + X_OFF;
  float* resid = ws + RES_OFF;
  float* o     = ws + O_OFF;
  float* xr    = ws + XR_OFF;
  float* xc    = ws + XC_OFF;
  float* xdbl  = ws + XDBL_OFF;
  float* delta = ws + DELTA_OFF;
  float* h1f   = ws + H1F_OFF;
  float* h2    = ws + H2_OFF;
  ushort2* P   = (ushort2*)(ws + P_OFF);

  __hip_bfloat16* xlnb  = (__hip_bfloat16*)(ws + XLNB_OFF);
  __hip_bfloat16* xdblb = (__hip_bfloat16*)(ws + XDBLB_OFF);
  __hip_bfloat16* xcb   = (__hip_bfloat16*)(ws + XCB_OFF);
  __hip_bfloat16* ygb   = (__hip_bfloat16*)(ws + YGB_OFF);
  __hip_bfloat16* hnb   = (__hip_bfloat16*)(ws + HNB_OFF);
  __hip_bfloat16* h1b   = (__hip_bfloat16*)(ws + H1B_OFF);
  __hip_bfloat16* idsb  = (__hip_bfloat16*)(ws + IDSB_OFF);
  __hip_bfloat16* wemb  = (__hip_bfloat16*)(ws + WEMB_OFF);
  __hip_bfloat16* wbin  = (__hip_bfloat16*)(ws + WBIN_OFF);
  __hip_bfloat16* wbx   = (__hip_bfloat16*)(ws + WBX_OFF);
  __hip_bfloat16* wbdt  = (__hip_bfloat16*)(ws + WBDT_OFF);
  __hip_bfloat16* wbout = (__hip_bfloat16*)(ws + WBOUT_OFF);
  __hip_bfloat16* wb1   = (__hip_bfloat16*)(ws + WB1_OFF);
  __hip_bfloat16* wb2   = (__hip_bfloat16*)(ws + WB2_OFF);

  // 0. cast weights + input to bf16 (one launch, 8 segments)
  CastArgs ca;
  ca.seg[0] = { input_ids, idsb,  (int)(ROWS * Vv / 4) };
  ca.seg[1] = { emb_W,     wemb,  (int)(DMc * Vv / 4) };
  ca.seg[2] = { inproj_W,  wbin,  (int)(2 * NLc * 2 * DIc * DMc / 4) };
  ca.seg[3] = { xproj_W,   wbx,   (int)(2 * NLc * 48 * DIc / 4) };
  ca.seg[4] = { dtproj_W,  wbdt,  (int)(2 * NLc * DIc * DTRc / 4) };
  ca.seg[5] = { outproj_W, wbout, (int)(2 * NLc * DMc * DIc / 4) };
  ca.seg[6] = { lin_W1,    wb1,   (int)(NLc * HIDc * Ls / 4) };
  ca.seg[7] = { lin_W2,    wb2,   (int)(NLc * Ls * HIDc / 4) };
  cast8_k<<<dim3(128, 8, 1), 256, 0, stream>>>(ca);

  // 1. embedding: x = ids @ emb_W^T + emb_b   (2048x256x256)
  gemm_bf<0, false><<<dim3(4, 32, 1), 256, 0, stream>>>(
      idsb, Vv, 0, wemb, Vv, 0, emb_b, 0, x, nullptr, DMc, 0, ROWS, DMc, Vv);
  copy_k<<<(int)(SZ_X / 256), 256, 0, stream>>>(x, resid);

  for (int i = 0; i < NLc; i++) {
    ln_dm_k<<<dim3(ROWS, 1, 2), 256, 0, stream>>>(x, ln_g, ln_b, xlnb, i);
    // inproj: 2048 x 1024 x 256
    gemm_bf<0, false><<<dim3(16, 32, 2), 256, 0, stream>>>(
        xlnb, DMc, (long)SZ_X,
        wbin + (size_t)i * 2 * DIc * DMc, DMc, (long)NLc * 2 * DIc * DMc,
        inproj_b + (size_t)i * 2 * DIc, (long)NLc * 2 * DIc,
        xr, nullptr, 2 * DIc, (long)SZ_XR, ROWS, 2 * DIc, DMc);
    conv_silu_k<<<dim3(ROWS * DIc / 256, 1, 2), 256, 0, stream>>>(
        xr, conv_w, conv_b, xc, xcb, i);
    // xproj: 2048 x 48 x 512 (f32 + bf16 outs)
    gemm_bf<0, true><<<dim3(1, 32, 2), 256, 0, stream>>>(
        xcb, DIc, (long)SZ_XC,
        wbx + (size_t)i * 48 * DIc, DIc, (long)NLc * 48 * DIc,
        nullptr, 0, xdbl, xdblb, 48, (long)SZ_XD, ROWS, 48, DIc);
    // dtproj + softplus: 2048 x 512 x 16
    gemm_bf<2, false><<<dim3(8, 32, 2), 256, 0, stream>>>(
        xdblb, 48, (long)SZ_XD,
        wbdt + (size_t)i * DIc * DTRc, DTRc, (long)NLc * DIc * DTRc,
        dtproj_b + (size_t)i * DIc, (long)NLc * DIc,
        delta, nullptr, DIc, (long)SZ_XC, ROWS, DIc, DTRc);
    // chunked selective scan + gate (3 passes, 16 n-states/thread)
    scan_p1<<<dim3(2 * NCH * Bb, 1, 2), 256, 0, stream>>>(
        delta, xc, xdbl, A_log, P, i);
    scan_mid<<<dim3(NCHAIN / 256, 1, 1), 256, 0, stream>>>(P);
    scan_p2<<<dim3(2 * NCH * Bb, 1, 2), 256, 0, stream>>>(
        delta, xc, xdbl, xr, A_log, Dp, P, ygb, i);
    // outproj: 2048 x 256 x 512
    gemm_bf<0, false><<<dim3(4, 32, 2), 256, 0, stream>>>(
        ygb, DIc, (long)SZ_XC,
        wbout + (size_t)i * DMc * DIc, DIc, (long)NLc * DMc * DIc,
        outproj_b + (size_t)i * DMc, (long)NLc * DMc,
        o, nullptr, DMc, (long)SZ_X, ROWS, DMc, DIc);
    combine_k<<<(int)(SZ_X / 256), 256, 0, stream>>>(x, o);
    // MLP over L axis
    mlp_norm_k<<<Bb * DMc, 256, 0, stream>>>(
        x, lin_norm_w + (size_t)i * Ls, lin_norm_b + (size_t)i * Ls, hnb, i == 0 ? 1 : 0);
    gemm_bf<1, true><<<dim3(8, 16, 1), 256, 0, stream>>>(
        hnb, Ls, 0, wb1 + (size_t)i * HIDc * Ls, Ls, 0,
        lin_b1 + (size_t)i * HIDc, 0, h1f, h1b, HIDc, 0, Bb * DMc, HIDc, Ls);
    gemm_bf<0, false><<<dim3(8, 16, 1), 256, 0, stream>>>(
        h1b, HIDc, 0, wb2 + (size_t)i * Ls * HIDc, HIDc, 0,
        lin_b2 + (size_t)i * Ls, 0, h2, nullptr, Ls, 0, Bb * DMc, Ls, HIDc);
    addback_k<<<(int)(SZ_X / 256), 256, 0, stream>>>(x, h2);
  }
  ln_final_k<<<ROWS, 256, 0, stream>>>(x, resid, normf_g, normf_b, out);
}